// Round 24
// baseline (124.950 us; speedup 1.0000x reference)
//
#include <hip/hip_runtime.h>

// Problem geometry (fixed by setup_inputs)
#define BB 32
#define DD 64
#define HWSZ 4096                  // H*W
#define KK 1024
#define NPIX (BB*HWSZ)             // 131072
#define NELEM (NPIX*DD)            // 8388608

// Output layout (concatenated float32)
#define IDX_OUT_OFF NELEM
#define LOSS_OFF (IDX_OUT_OFF + NPIX)

// Workspace layout (bytes)
#define WS_E2    0                        // 4 KB
#define WS_EBH   4096                     // 128 KB  B-frags hi
#define WS_EBL   (WS_EBH + KK*DD*2)       // 128 KB  B-frags lo
#define WS_IDX   (WS_EBL + KK*DD*2)       // 512 KB
#define WS_LIST  (WS_IDX + NPIX*4)        // 512 KB
#define WS_CNT   (WS_LIST + NPIX*4)       // 64 B: cnt@+0, loss-delta double@+8
#define WS_PART  (WS_CNT + 64)            // 16 KB
#define WS_ZROWS (WS_PART + 16384)        // packed z rows (full-exact rows)

#define PXB 128
#define ZSTR 129                   // zsh row stride (A-frag bank spread)

// Positive shift keeps all scores > 0 (sign-free key packing); BAND budget
// as rounds 17-23 (fast-vs-ref ~2e-5 + 10-bit clearing <= 6e-5 pairwise).
#define SHIFT 0.25f
#define BAND 2.5e-4f

typedef __attribute__((ext_vector_type(8))) short short8v;
typedef __attribute__((ext_vector_type(4))) float float4v;

__device__ __forceinline__ unsigned short bf16_rne(float f) {
    unsigned u = __float_as_uint(f);
    u += 0x7fffu + ((u >> 16) & 1u);
    return (unsigned short)(u >> 16);
}
__device__ __forceinline__ float bf16_tof(unsigned short h) {
    return __uint_as_float(((unsigned)h) << 16);
}

// numpy-style fp32 sum of 64 squares (squares rounded separately; no FMA).
__device__ __forceinline__ float np_sumsq64(const float* a) {
#pragma clang fp contract(off)
    float r0=0.f,r1=0.f,r2=0.f,r3=0.f,r4=0.f,r5=0.f,r6=0.f,r7=0.f;
#pragma unroll
    for (int i = 0; i < 64; i += 8) {
        r0 += a[i+0]*a[i+0]; r1 += a[i+1]*a[i+1];
        r2 += a[i+2]*a[i+2]; r3 += a[i+3]*a[i+3];
        r4 += a[i+4]*a[i+4]; r5 += a[i+5]*a[i+5];
        r6 += a[i+6]*a[i+6]; r7 += a[i+7]*a[i+7];
    }
    return ((r0+r1)+(r2+r3))+((r4+r5)+(r6+r7));
}

__device__ __forceinline__ float np_sumsq64_lds(const float* sh) {
#pragma clang fp contract(off)
    float r0=0.f,r1=0.f,r2=0.f,r3=0.f,r4=0.f,r5=0.f,r6=0.f,r7=0.f;
#pragma unroll
    for (int i = 0; i < 64; i += 8) {
        float a0=sh[i+0],a1=sh[i+1],a2=sh[i+2],a3=sh[i+3];
        float a4=sh[i+4],a5=sh[i+5],a6=sh[i+6],a7=sh[i+7];
        r0 += a0*a0; r1 += a1*a1; r2 += a2*a2; r3 += a3*a3;
        r4 += a4*a4; r5 += a5*a5; r6 += a6*a6; r7 += a7*a7;
    }
    return ((r0+r1)+(r2+r3))+((r4+r5)+(r6+r7));
}

__device__ __forceinline__ float np_sumsq64_str(const float* sh, int stride) {
#pragma clang fp contract(off)
    float r0=0.f,r1=0.f,r2=0.f,r3=0.f,r4=0.f,r5=0.f,r6=0.f,r7=0.f;
#pragma unroll
    for (int i = 0; i < 64; i += 8) {
        float a0=sh[(i+0)*stride],a1=sh[(i+1)*stride];
        float a2=sh[(i+2)*stride],a3=sh[(i+3)*stride];
        float a4=sh[(i+4)*stride],a5=sh[(i+5)*stride];
        float a6=sh[(i+6)*stride],a7=sh[(i+7)*stride];
        r0 += a0*a0; r1 += a1*a1; r2 += a2*a2; r3 += a3*a3;
        r4 += a4*a4; r5 += a5*a5; r6 += a6*a6; r7 += a7*a7;
    }
    return ((r0+r1)+(r2+r3))+((r4+r5)+(r6+r7));
}

// ---------------------------------------------------------------------------
// Prep (merged): B-fragments of the hi/lo bf16 split of emb^T + e2 table.
__global__ __launch_bounds__(256) void vq_prep(const float* __restrict__ emb,
                                               short* __restrict__ ebh,
                                               short* __restrict__ ebl,
                                               float* __restrict__ e2) {
    int t    = blockIdx.x * 256 + threadIdx.x;   // 8192 = 128 slots * 64 lanes
    int l    = t & 63;
    int slot = t >> 6;
    int ct = slot >> 1, ks = slot & 1;
    int code  = ct*16 + (l & 15);
    int dbase = ks*32 + (l >> 4)*8;
    const float* ep = emb + (size_t)code*DD + dbase;
    short8v h, lo;
#pragma unroll
    for (int j = 0; j < 8; ++j) {
        float v = ep[j];
        unsigned short hh = bf16_rne(v);
        h[j]  = (short)hh;
        lo[j] = (short)bf16_rne(v - bf16_tof(hh));
    }
    ((short8v*)ebh)[t] = h;
    ((short8v*)ebl)[t] = lo;

    if (blockIdx.x < 4) {                        // e2: 1024 threads total
        int k = blockIdx.x * 256 + threadIdx.x;
        float ek[DD];
        const float4* p = reinterpret_cast<const float4*>(emb + (size_t)k * DD);
#pragma unroll
        for (int q = 0; q < 16; ++q) {
            float4 v = p[q];
            ek[4*q+0]=v.x; ek[4*q+1]=v.y; ek[4*q+2]=v.z; ek[4*q+3]=v.w;
        }
        e2[k] = np_sumsq64(ek);
    }
}

// ---------------------------------------------------------------------------
// Main (fused): 128 px/block x 1024 codes via bf16 MFMA (3-pass hi/lo).
// Round-24: LDS staging with PREFETCH DISTANCE 2 (round-23's flaw: tile
// loaded and published in the SAME iter -> barrier stalls on L2 latency).
// Now: at iter ct, load tile ct+1 into regs; publish tile ct (loaded a full
// iteration ago); barrier; score prev; MFMA ct. Post-loop LDS arrays
// overlay the dead staging buffer (LDS 50.7 -> ~40 KB). Argmin arithmetic
// bit-identical to rounds 17-23.
__global__ __launch_bounds__(256, 4) void vq_main(
        const float* __restrict__ z, const float* __restrict__ emb,
        const short* __restrict__ ebh, const short* __restrict__ ebl,
        const float* __restrict__ e2,
        int* __restrict__ idx, int* __restrict__ list, int* __restrict__ cnt,
        float* __restrict__ zrows, int zcap,
        float* __restrict__ out, double* __restrict__ partial) {
    __shared__ float zsh[DD * ZSTR];               // 33024 B
    __shared__ __align__(16) char ovl[8192];       // staging buf / post-loop
    short8v* sbp    = (short8v*)ovl;               // sb[buf][half][slot]
    int*     idx_loc= (int*)ovl;                   // post-loop overlay
    int*     flpx   = (int*)(ovl + 512);
    int*     flslot = (int*)(ovl + 1024);
    int*     q_px   = (int*)(ovl + 1536);
    int*     q_k1   = (int*)(ovl + 2048);
    int*     q_k2   = (int*)(ovl + 2560);
    int*     cnts   = (int*)(ovl + 3072);          // [0]=nfl [1]=n2c
    double*  sred   = (double*)(ovl + 4096);       // 2048 B

    const int tid = threadIdx.x;
    const int w   = tid >> 6;
    const int l   = tid & 63;
    const int lr  = l & 15;
    const int lg  = l >> 4;
    const int b   = blockIdx.x >> 5;          // 32 blocks per image
    const int hw0 = (blockIdx.x & 31) * PXB;
    const float* zb = z + (size_t)b*(DD*HWSZ) + hw0;
    const short8v* EBH = (const short8v*)ebh;
    const short8v* EBL = (const short8v*)ebl;
    const int slot = tid & 127, half = tid >> 7;   // staging role
    const short8v* EBX = half ? EBL : EBH;

    {   // coalesced stage: 2 d-rows per iteration (256 thr = 2 x 128 px)
        const int row = tid >> 7, col = tid & 127;
#pragma unroll 8
        for (int d0 = 0; d0 < DD; d0 += 2)
            zsh[(d0+row)*ZSTR + col] = zb[(size_t)(d0+row)*HWSZ + col];
    }
    // B-frag tile 0 into buf 0
    sbp[half*128 + slot] = EBX[slot];
    __syncthreads();

    // A-frags from LDS. ah/al[rt][ks]; elem j <-> d = ks*32+lg*8+j.
    short8v ah[2][2], al[2][2];
#pragma unroll
    for (int rt = 0; rt < 2; ++rt) {
#pragma unroll
        for (int ks = 0; ks < 2; ++ks) {
            int px = w*32 + rt*16 + lr;
            int dbase = ks*32 + lg*8;
#pragma unroll
            for (int j = 0; j < 8; ++j) {
                float v = zsh[(dbase + j)*ZSTR + px];
                unsigned short hh = bf16_rne(v);
                ah[rt][ks][j] = (short)hh;
                al[rt][ks][j] = (short)bf16_rne(v - bf16_tof(hh));
            }
        }
    }

    // packed top-3 keys only (no index registers)
    float b1a[2][4], b2a[2][4], b3a[2][4];
#pragma unroll
    for (int rt = 0; rt < 2; ++rt)
#pragma unroll
        for (int r = 0; r < 4; ++r) {
            b1a[rt][r] = 3.4e38f; b2a[rt][r] = 3.4e38f; b3a[rt][r] = 3.4e38f;
        }

    float4v  accP[2];
    float    e2P;
    unsigned kfP;
    short8v  stgC;

    // ---- peel ct = 0: prefetch tile 1, MFMA tile 0 from LDS buf 0 ----
    {
        stgC = EBX[128 + slot];                    // tile 1 (arrives during peel)
        short8v bh0 = sbp[l],       bh1 = sbp[64+l];
        short8v bl0 = sbp[128+l],   bl1 = sbp[192+l];
        e2P = e2[lr] + SHIFT;
        kfP = (unsigned)lr;
#pragma unroll
        for (int rt = 0; rt < 2; ++rt) {
            float4v acc = {0.f, 0.f, 0.f, 0.f};
            acc = __builtin_amdgcn_mfma_f32_16x16x32_bf16(ah[rt][0], bh0, acc, 0,0,0);
            acc = __builtin_amdgcn_mfma_f32_16x16x32_bf16(ah[rt][1], bh1, acc, 0,0,0);
            acc = __builtin_amdgcn_mfma_f32_16x16x32_bf16(ah[rt][0], bl0, acc, 0,0,0);
            acc = __builtin_amdgcn_mfma_f32_16x16x32_bf16(ah[rt][1], bl1, acc, 0,0,0);
            acc = __builtin_amdgcn_mfma_f32_16x16x32_bf16(al[rt][0], bh0, acc, 0,0,0);
            acc = __builtin_amdgcn_mfma_f32_16x16x32_bf16(al[rt][1], bh1, acc, 0,0,0);
            accP[rt] = acc;
        }
    }

#pragma unroll 1
    for (int ct = 1; ct < 64; ++ct) {
        const int base = (ct & 1) * 256;
        // (1) prefetch tile ct+1 (wraps at end; harmless)
        short8v stgN = EBX[((ct+1) & 63)*128 + slot];
        // (2) publish tile ct (loaded a FULL iteration ago -> data arrived)
        sbp[base + half*128 + slot] = stgC;
        __syncthreads();

        // (3) process PREVIOUS iteration's scores (covers MFMA ds_reads)
#pragma unroll
        for (int rt = 0; rt < 2; ++rt)
#pragma unroll
            for (int r = 0; r < 4; ++r) {
                float s = __builtin_fmaf(-2.f, accP[rt][r], e2P);
                float p = __uint_as_float(
                    (__float_as_uint(s) & ~1023u) | kfP);
                float ob1 = b1a[rt][r], ob2 = b2a[rt][r];
                b1a[rt][r] = fminf(ob1, p);
                b2a[rt][r] = __builtin_amdgcn_fmed3f(ob1, ob2, p);
                b3a[rt][r] = __builtin_amdgcn_fmed3f(ob2, b3a[rt][r], p);
            }

        // (4) MFMA chain from LDS (same accumulation order as r17-23)
        {
            short8v bh0 = sbp[base + l],     bh1 = sbp[base + 64+l];
            short8v bl0 = sbp[base + 128+l], bl1 = sbp[base + 192+l];
#pragma unroll
            for (int rt = 0; rt < 2; ++rt) {
                float4v acc = {0.f, 0.f, 0.f, 0.f};
                acc = __builtin_amdgcn_mfma_f32_16x16x32_bf16(ah[rt][0], bh0, acc, 0,0,0);
                acc = __builtin_amdgcn_mfma_f32_16x16x32_bf16(ah[rt][1], bh1, acc, 0,0,0);
                acc = __builtin_amdgcn_mfma_f32_16x16x32_bf16(ah[rt][0], bl0, acc, 0,0,0);
                acc = __builtin_amdgcn_mfma_f32_16x16x32_bf16(ah[rt][1], bl1, acc, 0,0,0);
                acc = __builtin_amdgcn_mfma_f32_16x16x32_bf16(al[rt][0], bh0, acc, 0,0,0);
                acc = __builtin_amdgcn_mfma_f32_16x16x32_bf16(al[rt][1], bh1, acc, 0,0,0);
                accP[rt] = acc;
            }
        }
        e2P = e2[ct*16 + lr] + SHIFT;
        kfP = (unsigned)(ct*16 + lr);
        stgC = stgN;
    }

    // ---- drain: scores of ct = 63 (registers only) ----
#pragma unroll
    for (int rt = 0; rt < 2; ++rt)
#pragma unroll
        for (int r = 0; r < 4; ++r) {
            float s = __builtin_fmaf(-2.f, accP[rt][r], e2P);
            float p = __uint_as_float((__float_as_uint(s) & ~1023u) | kfP);
            float ob1 = b1a[rt][r], ob2 = b2a[rt][r];
            b1a[rt][r] = fminf(ob1, p);
            b2a[rt][r] = __builtin_amdgcn_fmed3f(ob1, ob2, p);
            b3a[rt][r] = __builtin_amdgcn_fmed3f(ob2, b3a[rt][r], p);
        }

    // staging buffer now dead; reuse ovl for queues/epilogue
    __syncthreads();
    if (tid < 2) cnts[tid] = 0;
    __syncthreads();
    int& nfl = cnts[0];
    int& n2c = cnts[1];

#pragma unroll
    for (int rt = 0; rt < 2; ++rt) {
#pragma unroll
        for (int r = 0; r < 4; ++r) {
            float b1 = b1a[rt][r], b2 = b2a[rt][r], b3 = b3a[rt][r];
#pragma unroll
            for (int m = 1; m < 16; m <<= 1) {   // sorted-triple min-merge
                float o1 = __shfl_xor(b1, m, 64);
                float o2 = __shfl_xor(b2, m, 64);
                float o3 = __shfl_xor(b3, m, 64);
                float mx  = fmaxf(b1, o1);
                float mn2 = fminf(b2, o2);
                float n1 = fminf(b1, o1);
                float n2 = fminf(mx, mn2);
                float n3 = fminf(fminf(fmaxf(mn2, mx), fmaxf(b2, o2)),
                                 fminf(b3, o3));
                b1 = n1; b2 = n2; b3 = n3;
            }
            if (lr == 0) {
                int i1 = (int)(__float_as_uint(b1) & 1023u);   // all keys > 0
                int pxl = w*32 + rt*16 + lg*4 + r;             // local pixel
                int n   = b*HWSZ + hw0 + pxl;
                idx[n] = i1;
                idx_loc[pxl] = i1;
                if (b2 - b1 <= BAND) {
                    if (b3 - b1 <= BAND) {                 // 3+ in band: full
                        int p = atomicAdd(cnt, 1);
                        list[p] = n;
                        int j = atomicAdd(&nfl, 1);
                        flpx[j] = pxl; flslot[j] = p;
                    } else {                               // exactly {i1,i2}
                        int i2 = (int)(__float_as_uint(b2) & 1023u);
                        int j = atomicAdd(&n2c, 1);
                        q_px[j] = pxl; q_k1[j] = i1; q_k2[j] = i2;
                    }
                }
            }
        }
    }

    __syncthreads();
    // ---- 2-candidate exact resolve (ref fp32 bits), one thread per row ----
    if (tid < n2c) {
        int px = q_px[tid], k1 = q_k1[tid], k2 = q_k2[tid];
        float z2 = np_sumsq64_str(&zsh[px], ZSTR);
        const float* ep1 = emb + (size_t)k1 * DD;
        const float* ep2 = emb + (size_t)k2 * DD;
        float s1 = 0.f, s2 = 0.f;
#pragma unroll
        for (int d = 0; d < DD; ++d) {                 // d-ascending chains
            float zd = zsh[d*ZSTR + px];
            s1 = __builtin_fmaf(zd, ep1[d], s1);
            s2 = __builtin_fmaf(zd, ep2[d], s2);
        }
        float B1v, B2v;
        {
#pragma clang fp contract(off)
            float A1 = z2 + e2[k1]; B1v = __builtin_fmaf(-2.f, s1, A1);
            float A2 = z2 + e2[k2]; B2v = __builtin_fmaf(-2.f, s2, A2);
        }
        int win;
        if (k1 < k2) win = (B2v < B1v) ? k2 : k1;      // first-min tie-break
        else         win = (B1v < B2v) ? k1 : k2;
        idx[b*HWSZ + hw0 + px] = win;
        idx_loc[px] = win;
    }

    // ---- packed z copy for full-exact rows (coalesced) ----
    __syncthreads();
    int nf = nfl;
    for (int j0 = 0; j0 < nf; j0 += 4) {
        int jj = j0 + (tid >> 6);
        if (jj < nf) {
            int sl = flslot[jj];
            if (sl < zcap) {
                int d = tid & 63;
                zrows[(size_t)sl*64 + d] = zsh[d*ZSTR + flpx[jj]];
            }
        }
    }
    __syncthreads();

    // ---- fused epilogue: 2 threads per px (d-halves); z from LDS ----
    {
        const int px = tid & 127;
        const int dh = tid >> 7;              // 0 or 1: d in [dh*32, dh*32+32)
        const int ki = idx_loc[px];
        const float4* ep = reinterpret_cast<const float4*>(
                               emb + (size_t)ki*DD + dh*32);
        float* op = out + (size_t)b*(DD*HWSZ) + (size_t)(dh*32)*HWSZ + hw0 + px;
        float lsum = 0.f;
#pragma unroll
        for (int q = 0; q < 8; ++q) {
            float4 v = ep[q];
            int d = dh*32 + 4*q;
            float z0 = zsh[(d+0)*ZSTR + px];
            float z1 = zsh[(d+1)*ZSTR + px];
            float z2v = zsh[(d+2)*ZSTR + px];
            float z3 = zsh[(d+3)*ZSTR + px];
            op[(size_t)(4*q+0)*HWSZ] = v.x;
            op[(size_t)(4*q+1)*HWSZ] = v.y;
            op[(size_t)(4*q+2)*HWSZ] = v.z;
            op[(size_t)(4*q+3)*HWSZ] = v.w;
            float f0 = v.x - z0, f1 = v.y - z1, f2 = v.z - z2v, f3 = v.w - z3;
            lsum = __builtin_fmaf(f0, f0, lsum);
            lsum = __builtin_fmaf(f1, f1, lsum);
            lsum = __builtin_fmaf(f2, f2, lsum);
            lsum = __builtin_fmaf(f3, f3, lsum);
        }
        if (dh == 0) out[IDX_OUT_OFF + b*HWSZ + hw0 + px] = (float)ki;
        sred[tid] = (double)lsum;
    }
    __syncthreads();
#pragma unroll
    for (int sdown = 128; sdown > 0; sdown >>= 1) {
        if (tid < sdown) sred[tid] += sred[tid + sdown];
        __syncthreads();
    }
    if (tid == 0) partial[blockIdx.x] = sred[0];
}

// ---------------------------------------------------------------------------
// Full exact pass v8: ONE BLOCK per rare flagged row (3+ in band). Computes
// the true ref-fp32 argmin AND patches the fused outputs.
__global__ __launch_bounds__(256) void vq_exact8(
        const float* __restrict__ z, const float* __restrict__ emb,
        const float* __restrict__ e2, const float* __restrict__ zrows,
        const int* __restrict__ list, const int* __restrict__ cnt,
        int zcap, int* __restrict__ idx, float* __restrict__ out,
        double* __restrict__ delta) {
    __shared__ float zsh[DD];
    __shared__ float rbv[256];
    __shared__ int   rbi[256];
    __shared__ double dred[64];
    const int tid = threadIdx.x;
    const int C   = *cnt;

    for (int i = blockIdx.x; i < C; i += gridDim.x) {
        const int n = list[i];
        if (tid < 64) {
            if (i < zcap) {
                zsh[tid] = zrows[(size_t)i*64 + tid];      // coalesced line
            } else {
                zsh[tid] = z[(size_t)(n>>12)*(DD*HWSZ) + (n&4095)
                             + (size_t)tid*HWSZ];
            }
        }
        __syncthreads();

        const float z2 = np_sumsq64_lds(zsh);

        float bestv = 3.4e38f; int bi = 0x7fffffff;
#pragma unroll
        for (int c = 0; c < 4; ++c) {                  // k = tid + c*256, asc
            int k = c*256 + tid;
            const float4* ep = reinterpret_cast<const float4*>(emb + (size_t)k*DD);
            float s = 0.f;
#pragma unroll
            for (int q = 0; q < 16; ++q) {             // d-ascending chain
                float4 v = ep[q];
                s = __builtin_fmaf(zsh[4*q+0], v.x, s);
                s = __builtin_fmaf(zsh[4*q+1], v.y, s);
                s = __builtin_fmaf(zsh[4*q+2], v.z, s);
                s = __builtin_fmaf(zsh[4*q+3], v.w, s);
            }
            float Bv;
            {
#pragma clang fp contract(off)
                float A = z2 + e2[k];
                Bv = __builtin_fmaf(-2.f, s, A);
            }
            if (Bv < bestv) { bestv = Bv; bi = k; }    // first-min (k asc)
        }

        rbv[tid] = bestv; rbi[tid] = bi;
        __syncthreads();
#pragma unroll
        for (int sdown = 128; sdown > 0; sdown >>= 1) {
            if (tid < sdown) {
                float ov = rbv[tid + sdown]; int oi = rbi[tid + sdown];
                if (ov < rbv[tid] || (ov == rbv[tid] && oi < rbi[tid])) {
                    rbv[tid] = ov; rbi[tid] = oi;
                }
            }
            __syncthreads();
        }
        const int win = rbi[0];
        const int old = idx[n];
        if (win != old) {                               // block-uniform branch
            const int bq = n >> 12, hw = n & 4095;
            if (tid < 64) {
                float zd = zsh[tid];
                float en = emb[(size_t)win*DD + tid];
                float eo = emb[(size_t)old*DD + tid];
                out[(size_t)bq*(DD*HWSZ) + (size_t)tid*HWSZ + hw] = en;
                float dn = en - zd, dl = eo - zd;
                dred[tid] = (double)(dn*dn) - (double)(dl*dl);
            }
            __syncthreads();
            if (tid == 0) {
                double s = 0.0;
                for (int j = 0; j < 64; ++j) s += dred[j];
                atomicAdd(delta, s);
                idx[n] = win;
                out[IDX_OUT_OFF + n] = (float)win;
            }
        }
        __syncthreads();
    }
}

// ---------------------------------------------------------------------------
__global__ __launch_bounds__(256) void vq_finalize(
        const double* __restrict__ part, const double* __restrict__ delta,
        float* __restrict__ out) {
    __shared__ double sred[256];
    int t = threadIdx.x;
    sred[t] = part[t] + part[t + 256] + part[t + 512] + part[t + 768];
    __syncthreads();
#pragma unroll
    for (int sdown = 128; sdown > 0; sdown >>= 1) {
        if (t < sdown) sred[t] += sred[t + sdown];
        __syncthreads();
    }
    if (t == 0) {
        double m = (sred[0] + *delta) / (double)NELEM;
        out[LOSS_OFF]     = (float)m;
        out[LOSS_OFF + 1] = (float)(0.25 * m);
    }
}

// ---------------------------------------------------------------------------
extern "C" void kernel_launch(void* const* d_in, const int* in_sizes, int n_in,
                              void* d_out, int out_size, void* d_ws, size_t ws_size,
                              hipStream_t stream) {
    const float* z   = (const float*)d_in[0];
    const float* emb = (const float*)d_in[1];
    float* out = (float*)d_out;
    char*  ws  = (char*)d_ws;

    float*  e2p   = (float*)(ws + WS_E2);
    short*  ebh   = (short*)(ws + WS_EBH);
    short*  ebl   = (short*)(ws + WS_EBL);
    int*    idxp  = (int*)(ws + WS_IDX);
    int*    lst   = (int*)(ws + WS_LIST);
    int*    cntp  = (int*)(ws + WS_CNT);
    double* delta = (double*)(ws + WS_CNT + 8);
    double* part  = (double*)(ws + WS_PART);
    float*  zrows = (float*)(ws + WS_ZROWS);

    long long zrem = (long long)ws_size - (long long)WS_ZROWS;
    int zcap = zrem > 0 ? (int)(zrem / 256) : 0;
    if (zcap > NPIX) zcap = NPIX;

    hipMemsetAsync(cntp, 0, 16, stream);     // cnt + loss delta
    vq_prep     <<<32,       256, 0, stream>>>(emb, ebh, ebl, e2p);
    vq_main     <<<NPIX/PXB, 256, 0, stream>>>(z, emb, ebh, ebl, e2p, idxp,
                                               lst, cntp, zrows, zcap,
                                               out, part);
    vq_exact8   <<<512,      256, 0, stream>>>(z, emb, e2p, zrows, lst, cntp,
                                               zcap, idxp, out, delta);
    vq_finalize <<<1,        256, 0, stream>>>(part, delta, out);
}

// Round 25
// 119.937 us; speedup vs baseline: 1.0418x; 1.0418x over previous
//
#include <hip/hip_runtime.h>

// Problem geometry (fixed by setup_inputs)
#define BB 32
#define DD 64
#define HWSZ 4096                  // H*W
#define KK 1024
#define NPIX (BB*HWSZ)             // 131072
#define NELEM (NPIX*DD)            // 8388608

// Output layout (concatenated float32)
#define IDX_OUT_OFF NELEM
#define LOSS_OFF (IDX_OUT_OFF + NPIX)

// Workspace layout (bytes)
#define WS_E2    0                        // 4 KB
#define WS_EBH   4096                     // 128 KB  B-frags hi
#define WS_EBL   (WS_EBH + KK*DD*2)       // 128 KB  B-frags lo
#define WS_IDX   (WS_EBL + KK*DD*2)       // 512 KB
#define WS_LIST  (WS_IDX + NPIX*4)        // 512 KB
#define WS_CNT   (WS_LIST + NPIX*4)       // 64 B: cnt@+0, loss-delta double@+8
#define WS_PART  (WS_CNT + 64)            // 16 KB
#define WS_ZROWS (WS_PART + 16384)        // packed z rows (full-exact rows)

#define PXB 128
#define ZSTR 128                   // round-25: UNPADDED -> zsh 32768 B; with
                                   // 8192 B overlay = exactly 40960 B LDS ->
                                   // 4 blocks/CU (round-24's 41.5 KB gave 3).
                                   // Stride-128 audit: stage/epilogue reads
                                   // lane-consecutive (free); A-frag build
                                   // 4-way on 32 one-time reads (negligible).

// Positive shift keeps all scores > 0 (sign-free key packing); BAND budget
// as rounds 17-24 (fast-vs-ref ~2e-5 + 10-bit clearing <= 6e-5 pairwise).
#define SHIFT 0.25f
#define BAND 2.5e-4f

typedef __attribute__((ext_vector_type(8))) short short8v;
typedef __attribute__((ext_vector_type(4))) float float4v;

__device__ __forceinline__ unsigned short bf16_rne(float f) {
    unsigned u = __float_as_uint(f);
    u += 0x7fffu + ((u >> 16) & 1u);
    return (unsigned short)(u >> 16);
}
__device__ __forceinline__ float bf16_tof(unsigned short h) {
    return __uint_as_float(((unsigned)h) << 16);
}

// numpy-style fp32 sum of 64 squares (squares rounded separately; no FMA).
__device__ __forceinline__ float np_sumsq64(const float* a) {
#pragma clang fp contract(off)
    float r0=0.f,r1=0.f,r2=0.f,r3=0.f,r4=0.f,r5=0.f,r6=0.f,r7=0.f;
#pragma unroll
    for (int i = 0; i < 64; i += 8) {
        r0 += a[i+0]*a[i+0]; r1 += a[i+1]*a[i+1];
        r2 += a[i+2]*a[i+2]; r3 += a[i+3]*a[i+3];
        r4 += a[i+4]*a[i+4]; r5 += a[i+5]*a[i+5];
        r6 += a[i+6]*a[i+6]; r7 += a[i+7]*a[i+7];
    }
    return ((r0+r1)+(r2+r3))+((r4+r5)+(r6+r7));
}

__device__ __forceinline__ float np_sumsq64_lds(const float* sh) {
#pragma clang fp contract(off)
    float r0=0.f,r1=0.f,r2=0.f,r3=0.f,r4=0.f,r5=0.f,r6=0.f,r7=0.f;
#pragma unroll
    for (int i = 0; i < 64; i += 8) {
        float a0=sh[i+0],a1=sh[i+1],a2=sh[i+2],a3=sh[i+3];
        float a4=sh[i+4],a5=sh[i+5],a6=sh[i+6],a7=sh[i+7];
        r0 += a0*a0; r1 += a1*a1; r2 += a2*a2; r3 += a3*a3;
        r4 += a4*a4; r5 += a5*a5; r6 += a6*a6; r7 += a7*a7;
    }
    return ((r0+r1)+(r2+r3))+((r4+r5)+(r6+r7));
}

__device__ __forceinline__ float np_sumsq64_str(const float* sh, int stride) {
#pragma clang fp contract(off)
    float r0=0.f,r1=0.f,r2=0.f,r3=0.f,r4=0.f,r5=0.f,r6=0.f,r7=0.f;
#pragma unroll
    for (int i = 0; i < 64; i += 8) {
        float a0=sh[(i+0)*stride],a1=sh[(i+1)*stride];
        float a2=sh[(i+2)*stride],a3=sh[(i+3)*stride];
        float a4=sh[(i+4)*stride],a5=sh[(i+5)*stride];
        float a6=sh[(i+6)*stride],a7=sh[(i+7)*stride];
        r0 += a0*a0; r1 += a1*a1; r2 += a2*a2; r3 += a3*a3;
        r4 += a4*a4; r5 += a5*a5; r6 += a6*a6; r7 += a7*a7;
    }
    return ((r0+r1)+(r2+r3))+((r4+r5)+(r6+r7));
}

// ---------------------------------------------------------------------------
// Prep (merged): B-fragments of the hi/lo bf16 split of emb^T + e2 table.
__global__ __launch_bounds__(256) void vq_prep(const float* __restrict__ emb,
                                               short* __restrict__ ebh,
                                               short* __restrict__ ebl,
                                               float* __restrict__ e2) {
    int t    = blockIdx.x * 256 + threadIdx.x;   // 8192 = 128 slots * 64 lanes
    int l    = t & 63;
    int slot = t >> 6;
    int ct = slot >> 1, ks = slot & 1;
    int code  = ct*16 + (l & 15);
    int dbase = ks*32 + (l >> 4)*8;
    const float* ep = emb + (size_t)code*DD + dbase;
    short8v h, lo;
#pragma unroll
    for (int j = 0; j < 8; ++j) {
        float v = ep[j];
        unsigned short hh = bf16_rne(v);
        h[j]  = (short)hh;
        lo[j] = (short)bf16_rne(v - bf16_tof(hh));
    }
    ((short8v*)ebh)[t] = h;
    ((short8v*)ebl)[t] = lo;

    if (blockIdx.x < 4) {                        // e2: 1024 threads total
        int k = blockIdx.x * 256 + threadIdx.x;
        float ek[DD];
        const float4* p = reinterpret_cast<const float4*>(emb + (size_t)k * DD);
#pragma unroll
        for (int q = 0; q < 16; ++q) {
            float4 v = p[q];
            ek[4*q+0]=v.x; ek[4*q+1]=v.y; ek[4*q+2]=v.z; ek[4*q+3]=v.w;
        }
        e2[k] = np_sumsq64(ek);
    }
}

// ---------------------------------------------------------------------------
// Main (fused): 128 px/block x 1024 codes via bf16 MFMA (3-pass hi/lo).
// LDS staging with prefetch distance 2 (round 24) + exact 40 KB LDS
// (round 25) -> 4 blocks/CU. Argmin arithmetic bit-identical to r17-24.
__global__ __launch_bounds__(256, 4) void vq_main(
        const float* __restrict__ z, const float* __restrict__ emb,
        const short* __restrict__ ebh, const short* __restrict__ ebl,
        const float* __restrict__ e2,
        int* __restrict__ idx, int* __restrict__ list, int* __restrict__ cnt,
        float* __restrict__ zrows, int zcap,
        float* __restrict__ out, double* __restrict__ partial) {
    __shared__ float zsh[DD * ZSTR];               // 32768 B
    __shared__ __align__(16) char ovl[8192];       // staging buf / post-loop
    short8v* sbp    = (short8v*)ovl;               // sb[buf][half][slot]
    int*     idx_loc= (int*)ovl;                   // post-loop overlay
    int*     flpx   = (int*)(ovl + 512);
    int*     flslot = (int*)(ovl + 1024);
    int*     q_px   = (int*)(ovl + 1536);
    int*     q_k1   = (int*)(ovl + 2048);
    int*     q_k2   = (int*)(ovl + 2560);
    int*     cnts   = (int*)(ovl + 3072);          // [0]=nfl [1]=n2c
    double*  sred   = (double*)(ovl + 4096);       // 2048 B

    const int tid = threadIdx.x;
    const int w   = tid >> 6;
    const int l   = tid & 63;
    const int lr  = l & 15;
    const int lg  = l >> 4;
    const int b   = blockIdx.x >> 5;          // 32 blocks per image
    const int hw0 = (blockIdx.x & 31) * PXB;
    const float* zb = z + (size_t)b*(DD*HWSZ) + hw0;
    const short8v* EBH = (const short8v*)ebh;
    const short8v* EBL = (const short8v*)ebl;
    const int slot = tid & 127, half = tid >> 7;   // staging role
    const short8v* EBX = half ? EBL : EBH;

    {   // coalesced stage: 2 d-rows per iteration (256 thr = 2 x 128 px)
        const int row = tid >> 7, col = tid & 127;
#pragma unroll 8
        for (int d0 = 0; d0 < DD; d0 += 2)
            zsh[(d0+row)*ZSTR + col] = zb[(size_t)(d0+row)*HWSZ + col];
    }
    // B-frag tile 0 into buf 0
    sbp[half*128 + slot] = EBX[slot];
    __syncthreads();

    // A-frags from LDS. ah/al[rt][ks]; elem j <-> d = ks*32+lg*8+j.
    short8v ah[2][2], al[2][2];
#pragma unroll
    for (int rt = 0; rt < 2; ++rt) {
#pragma unroll
        for (int ks = 0; ks < 2; ++ks) {
            int px = w*32 + rt*16 + lr;
            int dbase = ks*32 + lg*8;
#pragma unroll
            for (int j = 0; j < 8; ++j) {
                float v = zsh[(dbase + j)*ZSTR + px];
                unsigned short hh = bf16_rne(v);
                ah[rt][ks][j] = (short)hh;
                al[rt][ks][j] = (short)bf16_rne(v - bf16_tof(hh));
            }
        }
    }

    // packed top-3 keys only (no index registers)
    float b1a[2][4], b2a[2][4], b3a[2][4];
#pragma unroll
    for (int rt = 0; rt < 2; ++rt)
#pragma unroll
        for (int r = 0; r < 4; ++r) {
            b1a[rt][r] = 3.4e38f; b2a[rt][r] = 3.4e38f; b3a[rt][r] = 3.4e38f;
        }

    float4v  accP[2];
    float    e2P;
    unsigned kfP;
    short8v  stgC;

    // ---- peel ct = 0: prefetch tile 1, MFMA tile 0 from LDS buf 0 ----
    {
        stgC = EBX[128 + slot];                    // tile 1 (arrives during peel)
        short8v bh0 = sbp[l],       bh1 = sbp[64+l];
        short8v bl0 = sbp[128+l],   bl1 = sbp[192+l];
        e2P = e2[lr] + SHIFT;
        kfP = (unsigned)lr;
#pragma unroll
        for (int rt = 0; rt < 2; ++rt) {
            float4v acc = {0.f, 0.f, 0.f, 0.f};
            acc = __builtin_amdgcn_mfma_f32_16x16x32_bf16(ah[rt][0], bh0, acc, 0,0,0);
            acc = __builtin_amdgcn_mfma_f32_16x16x32_bf16(ah[rt][1], bh1, acc, 0,0,0);
            acc = __builtin_amdgcn_mfma_f32_16x16x32_bf16(ah[rt][0], bl0, acc, 0,0,0);
            acc = __builtin_amdgcn_mfma_f32_16x16x32_bf16(ah[rt][1], bl1, acc, 0,0,0);
            acc = __builtin_amdgcn_mfma_f32_16x16x32_bf16(al[rt][0], bh0, acc, 0,0,0);
            acc = __builtin_amdgcn_mfma_f32_16x16x32_bf16(al[rt][1], bh1, acc, 0,0,0);
            accP[rt] = acc;
        }
    }

#pragma unroll 1
    for (int ct = 1; ct < 64; ++ct) {
        const int base = (ct & 1) * 256;
        // (1) prefetch tile ct+1 (wraps at end; harmless)
        short8v stgN = EBX[((ct+1) & 63)*128 + slot];
        // (2) publish tile ct (loaded a FULL iteration ago -> data arrived)
        sbp[base + half*128 + slot] = stgC;
        __syncthreads();

        // (3) process PREVIOUS iteration's scores (covers MFMA ds_reads)
#pragma unroll
        for (int rt = 0; rt < 2; ++rt)
#pragma unroll
            for (int r = 0; r < 4; ++r) {
                float s = __builtin_fmaf(-2.f, accP[rt][r], e2P);
                float p = __uint_as_float(
                    (__float_as_uint(s) & ~1023u) | kfP);
                float ob1 = b1a[rt][r], ob2 = b2a[rt][r];
                b1a[rt][r] = fminf(ob1, p);
                b2a[rt][r] = __builtin_amdgcn_fmed3f(ob1, ob2, p);
                b3a[rt][r] = __builtin_amdgcn_fmed3f(ob2, b3a[rt][r], p);
            }

        // (4) MFMA chain from LDS (same accumulation order as r17-24)
        {
            short8v bh0 = sbp[base + l],     bh1 = sbp[base + 64+l];
            short8v bl0 = sbp[base + 128+l], bl1 = sbp[base + 192+l];
#pragma unroll
            for (int rt = 0; rt < 2; ++rt) {
                float4v acc = {0.f, 0.f, 0.f, 0.f};
                acc = __builtin_amdgcn_mfma_f32_16x16x32_bf16(ah[rt][0], bh0, acc, 0,0,0);
                acc = __builtin_amdgcn_mfma_f32_16x16x32_bf16(ah[rt][1], bh1, acc, 0,0,0);
                acc = __builtin_amdgcn_mfma_f32_16x16x32_bf16(ah[rt][0], bl0, acc, 0,0,0);
                acc = __builtin_amdgcn_mfma_f32_16x16x32_bf16(ah[rt][1], bl1, acc, 0,0,0);
                acc = __builtin_amdgcn_mfma_f32_16x16x32_bf16(al[rt][0], bh0, acc, 0,0,0);
                acc = __builtin_amdgcn_mfma_f32_16x16x32_bf16(al[rt][1], bh1, acc, 0,0,0);
                accP[rt] = acc;
            }
        }
        e2P = e2[ct*16 + lr] + SHIFT;
        kfP = (unsigned)(ct*16 + lr);
        stgC = stgN;
    }

    // ---- drain: scores of ct = 63 (registers only) ----
#pragma unroll
    for (int rt = 0; rt < 2; ++rt)
#pragma unroll
        for (int r = 0; r < 4; ++r) {
            float s = __builtin_fmaf(-2.f, accP[rt][r], e2P);
            float p = __uint_as_float((__float_as_uint(s) & ~1023u) | kfP);
            float ob1 = b1a[rt][r], ob2 = b2a[rt][r];
            b1a[rt][r] = fminf(ob1, p);
            b2a[rt][r] = __builtin_amdgcn_fmed3f(ob1, ob2, p);
            b3a[rt][r] = __builtin_amdgcn_fmed3f(ob2, b3a[rt][r], p);
        }

    // staging buffer now dead; reuse ovl for queues/epilogue
    __syncthreads();
    if (tid < 2) cnts[tid] = 0;
    __syncthreads();
    int& nfl = cnts[0];
    int& n2c = cnts[1];

#pragma unroll
    for (int rt = 0; rt < 2; ++rt) {
#pragma unroll
        for (int r = 0; r < 4; ++r) {
            float b1 = b1a[rt][r], b2 = b2a[rt][r], b3 = b3a[rt][r];
#pragma unroll
            for (int m = 1; m < 16; m <<= 1) {   // sorted-triple min-merge
                float o1 = __shfl_xor(b1, m, 64);
                float o2 = __shfl_xor(b2, m, 64);
                float o3 = __shfl_xor(b3, m, 64);
                float mx  = fmaxf(b1, o1);
                float mn2 = fminf(b2, o2);
                float n1 = fminf(b1, o1);
                float n2 = fminf(mx, mn2);
                float n3 = fminf(fminf(fmaxf(mn2, mx), fmaxf(b2, o2)),
                                 fminf(b3, o3));
                b1 = n1; b2 = n2; b3 = n3;
            }
            if (lr == 0) {
                int i1 = (int)(__float_as_uint(b1) & 1023u);   // all keys > 0
                int pxl = w*32 + rt*16 + lg*4 + r;             // local pixel
                int n   = b*HWSZ + hw0 + pxl;
                idx[n] = i1;
                idx_loc[pxl] = i1;
                if (b2 - b1 <= BAND) {
                    if (b3 - b1 <= BAND) {                 // 3+ in band: full
                        int p = atomicAdd(cnt, 1);
                        list[p] = n;
                        int j = atomicAdd(&nfl, 1);
                        flpx[j] = pxl; flslot[j] = p;
                    } else {                               // exactly {i1,i2}
                        int i2 = (int)(__float_as_uint(b2) & 1023u);
                        int j = atomicAdd(&n2c, 1);
                        q_px[j] = pxl; q_k1[j] = i1; q_k2[j] = i2;
                    }
                }
            }
        }
    }

    __syncthreads();
    // ---- 2-candidate exact resolve (ref fp32 bits), one thread per row ----
    if (tid < n2c) {
        int px = q_px[tid], k1 = q_k1[tid], k2 = q_k2[tid];
        float z2 = np_sumsq64_str(&zsh[px], ZSTR);
        const float* ep1 = emb + (size_t)k1 * DD;
        const float* ep2 = emb + (size_t)k2 * DD;
        float s1 = 0.f, s2 = 0.f;
#pragma unroll
        for (int d = 0; d < DD; ++d) {                 // d-ascending chains
            float zd = zsh[d*ZSTR + px];
            s1 = __builtin_fmaf(zd, ep1[d], s1);
            s2 = __builtin_fmaf(zd, ep2[d], s2);
        }
        float B1v, B2v;
        {
#pragma clang fp contract(off)
            float A1 = z2 + e2[k1]; B1v = __builtin_fmaf(-2.f, s1, A1);
            float A2 = z2 + e2[k2]; B2v = __builtin_fmaf(-2.f, s2, A2);
        }
        int win;
        if (k1 < k2) win = (B2v < B1v) ? k2 : k1;      // first-min tie-break
        else         win = (B1v < B2v) ? k1 : k2;
        idx[b*HWSZ + hw0 + px] = win;
        idx_loc[px] = win;
    }

    // ---- packed z copy for full-exact rows (coalesced) ----
    __syncthreads();
    int nf = nfl;
    for (int j0 = 0; j0 < nf; j0 += 4) {
        int jj = j0 + (tid >> 6);
        if (jj < nf) {
            int sl = flslot[jj];
            if (sl < zcap) {
                int d = tid & 63;
                zrows[(size_t)sl*64 + d] = zsh[d*ZSTR + flpx[jj]];
            }
        }
    }
    __syncthreads();

    // ---- fused epilogue: 2 threads per px (d-halves); z from LDS ----
    {
        const int px = tid & 127;
        const int dh = tid >> 7;              // 0 or 1: d in [dh*32, dh*32+32)
        const int ki = idx_loc[px];
        const float4* ep = reinterpret_cast<const float4*>(
                               emb + (size_t)ki*DD + dh*32);
        float* op = out + (size_t)b*(DD*HWSZ) + (size_t)(dh*32)*HWSZ + hw0 + px;
        float lsum = 0.f;
#pragma unroll
        for (int q = 0; q < 8; ++q) {
            float4 v = ep[q];
            int d = dh*32 + 4*q;
            float z0 = zsh[(d+0)*ZSTR + px];
            float z1 = zsh[(d+1)*ZSTR + px];
            float z2v = zsh[(d+2)*ZSTR + px];
            float z3 = zsh[(d+3)*ZSTR + px];
            op[(size_t)(4*q+0)*HWSZ] = v.x;
            op[(size_t)(4*q+1)*HWSZ] = v.y;
            op[(size_t)(4*q+2)*HWSZ] = v.z;
            op[(size_t)(4*q+3)*HWSZ] = v.w;
            float f0 = v.x - z0, f1 = v.y - z1, f2 = v.z - z2v, f3 = v.w - z3;
            lsum = __builtin_fmaf(f0, f0, lsum);
            lsum = __builtin_fmaf(f1, f1, lsum);
            lsum = __builtin_fmaf(f2, f2, lsum);
            lsum = __builtin_fmaf(f3, f3, lsum);
        }
        if (dh == 0) out[IDX_OUT_OFF + b*HWSZ + hw0 + px] = (float)ki;
        sred[tid] = (double)lsum;
    }
    __syncthreads();
#pragma unroll
    for (int sdown = 128; sdown > 0; sdown >>= 1) {
        if (tid < sdown) sred[tid] += sred[tid + sdown];
        __syncthreads();
    }
    if (tid == 0) partial[blockIdx.x] = sred[0];
}

// ---------------------------------------------------------------------------
// Full exact pass v8: ONE BLOCK per rare flagged row (3+ in band). Computes
// the true ref-fp32 argmin AND patches the fused outputs.
__global__ __launch_bounds__(256) void vq_exact8(
        const float* __restrict__ z, const float* __restrict__ emb,
        const float* __restrict__ e2, const float* __restrict__ zrows,
        const int* __restrict__ list, const int* __restrict__ cnt,
        int zcap, int* __restrict__ idx, float* __restrict__ out,
        double* __restrict__ delta) {
    __shared__ float zsh[DD];
    __shared__ float rbv[256];
    __shared__ int   rbi[256];
    __shared__ double dred[64];
    const int tid = threadIdx.x;
    const int C   = *cnt;

    for (int i = blockIdx.x; i < C; i += gridDim.x) {
        const int n = list[i];
        if (tid < 64) {
            if (i < zcap) {
                zsh[tid] = zrows[(size_t)i*64 + tid];      // coalesced line
            } else {
                zsh[tid] = z[(size_t)(n>>12)*(DD*HWSZ) + (n&4095)
                             + (size_t)tid*HWSZ];
            }
        }
        __syncthreads();

        const float z2 = np_sumsq64_lds(zsh);

        float bestv = 3.4e38f; int bi = 0x7fffffff;
#pragma unroll
        for (int c = 0; c < 4; ++c) {                  // k = tid + c*256, asc
            int k = c*256 + tid;
            const float4* ep = reinterpret_cast<const float4*>(emb + (size_t)k*DD);
            float s = 0.f;
#pragma unroll
            for (int q = 0; q < 16; ++q) {             // d-ascending chain
                float4 v = ep[q];
                s = __builtin_fmaf(zsh[4*q+0], v.x, s);
                s = __builtin_fmaf(zsh[4*q+1], v.y, s);
                s = __builtin_fmaf(zsh[4*q+2], v.z, s);
                s = __builtin_fmaf(zsh[4*q+3], v.w, s);
            }
            float Bv;
            {
#pragma clang fp contract(off)
                float A = z2 + e2[k];
                Bv = __builtin_fmaf(-2.f, s, A);
            }
            if (Bv < bestv) { bestv = Bv; bi = k; }    // first-min (k asc)
        }

        rbv[tid] = bestv; rbi[tid] = bi;
        __syncthreads();
#pragma unroll
        for (int sdown = 128; sdown > 0; sdown >>= 1) {
            if (tid < sdown) {
                float ov = rbv[tid + sdown]; int oi = rbi[tid + sdown];
                if (ov < rbv[tid] || (ov == rbv[tid] && oi < rbi[tid])) {
                    rbv[tid] = ov; rbi[tid] = oi;
                }
            }
            __syncthreads();
        }
        const int win = rbi[0];
        const int old = idx[n];
        if (win != old) {                               // block-uniform branch
            const int bq = n >> 12, hw = n & 4095;
            if (tid < 64) {
                float zd = zsh[tid];
                float en = emb[(size_t)win*DD + tid];
                float eo = emb[(size_t)old*DD + tid];
                out[(size_t)bq*(DD*HWSZ) + (size_t)tid*HWSZ + hw] = en;
                float dn = en - zd, dl = eo - zd;
                dred[tid] = (double)(dn*dn) - (double)(dl*dl);
            }
            __syncthreads();
            if (tid == 0) {
                double s = 0.0;
                for (int j = 0; j < 64; ++j) s += dred[j];
                atomicAdd(delta, s);
                idx[n] = win;
                out[IDX_OUT_OFF + n] = (float)win;
            }
        }
        __syncthreads();
    }
}

// ---------------------------------------------------------------------------
__global__ __launch_bounds__(256) void vq_finalize(
        const double* __restrict__ part, const double* __restrict__ delta,
        float* __restrict__ out) {
    __shared__ double sred[256];
    int t = threadIdx.x;
    sred[t] = part[t] + part[t + 256] + part[t + 512] + part[t + 768];
    __syncthreads();
#pragma unroll
    for (int sdown = 128; sdown > 0; sdown >>= 1) {
        if (t < sdown) sred[t] += sred[t + sdown];
        __syncthreads();
    }
    if (t == 0) {
        double m = (sred[0] + *delta) / (double)NELEM;
        out[LOSS_OFF]     = (float)m;
        out[LOSS_OFF + 1] = (float)(0.25 * m);
    }
}

// ---------------------------------------------------------------------------
extern "C" void kernel_launch(void* const* d_in, const int* in_sizes, int n_in,
                              void* d_out, int out_size, void* d_ws, size_t ws_size,
                              hipStream_t stream) {
    const float* z   = (const float*)d_in[0];
    const float* emb = (const float*)d_in[1];
    float* out = (float*)d_out;
    char*  ws  = (char*)d_ws;

    float*  e2p   = (float*)(ws + WS_E2);
    short*  ebh   = (short*)(ws + WS_EBH);
    short*  ebl   = (short*)(ws + WS_EBL);
    int*    idxp  = (int*)(ws + WS_IDX);
    int*    lst   = (int*)(ws + WS_LIST);
    int*    cntp  = (int*)(ws + WS_CNT);
    double* delta = (double*)(ws + WS_CNT + 8);
    double* part  = (double*)(ws + WS_PART);
    float*  zrows = (float*)(ws + WS_ZROWS);

    long long zrem = (long long)ws_size - (long long)WS_ZROWS;
    int zcap = zrem > 0 ? (int)(zrem / 256) : 0;
    if (zcap > NPIX) zcap = NPIX;

    hipMemsetAsync(cntp, 0, 16, stream);     // cnt + loss delta
    vq_prep     <<<32,       256, 0, stream>>>(emb, ebh, ebl, e2p);
    vq_main     <<<NPIX/PXB, 256, 0, stream>>>(z, emb, ebh, ebl, e2p, idxp,
                                               lst, cntp, zrows, zcap,
                                               out, part);
    vq_exact8   <<<512,      256, 0, stream>>>(z, emb, e2p, zrows, lst, cntp,
                                               zcap, idxp, out, delta);
    vq_finalize <<<1,        256, 0, stream>>>(part, delta, out);
}

// Round 26
// 119.898 us; speedup vs baseline: 1.0421x; 1.0003x over previous
//
#include <hip/hip_runtime.h>

// Problem geometry (fixed by setup_inputs)
#define BB 32
#define DD 64
#define HWSZ 4096                  // H*W
#define KK 1024
#define NPIX (BB*HWSZ)             // 131072
#define NELEM (NPIX*DD)            // 8388608

// Output layout (concatenated float32)
#define IDX_OUT_OFF NELEM
#define LOSS_OFF (IDX_OUT_OFF + NPIX)

// Workspace layout (bytes)
#define WS_E2    0                        // 4 KB
#define WS_EBH   4096                     // 128 KB  B-frags hi
#define WS_EBL   (WS_EBH + KK*DD*2)       // 128 KB  B-frags lo
#define WS_IDX   (WS_EBL + KK*DD*2)       // 512 KB
#define WS_LIST  (WS_IDX + NPIX*4)        // 512 KB
#define WS_CNT   (WS_LIST + NPIX*4)       // 64 B: cnt@+0, loss-delta double@+8
#define WS_PART  (WS_CNT + 64)            // 16 KB
#define WS_ZROWS (WS_PART + 16384)        // packed z rows (full-exact rows)

#define PXB 128
#define ZSTR 128                   // unpadded: zsh 32768 B + ovl 8192 = 40960

// Positive shift keeps all scores > 0 (sign-free key packing); BAND budget
// as rounds 17-25 (fast-vs-ref ~2e-5 + 10-bit clearing <= 6e-5 pairwise).
#define SHIFT 0.25f
#define BAND 2.5e-4f

typedef __attribute__((ext_vector_type(8))) short short8v;
typedef __attribute__((ext_vector_type(4))) float float4v;

__device__ __forceinline__ unsigned short bf16_rne(float f) {
    unsigned u = __float_as_uint(f);
    u += 0x7fffu + ((u >> 16) & 1u);
    return (unsigned short)(u >> 16);
}
__device__ __forceinline__ float bf16_tof(unsigned short h) {
    return __uint_as_float(((unsigned)h) << 16);
}

// numpy-style fp32 sum of 64 squares (squares rounded separately; no FMA).
__device__ __forceinline__ float np_sumsq64(const float* a) {
#pragma clang fp contract(off)
    float r0=0.f,r1=0.f,r2=0.f,r3=0.f,r4=0.f,r5=0.f,r6=0.f,r7=0.f;
#pragma unroll
    for (int i = 0; i < 64; i += 8) {
        r0 += a[i+0]*a[i+0]; r1 += a[i+1]*a[i+1];
        r2 += a[i+2]*a[i+2]; r3 += a[i+3]*a[i+3];
        r4 += a[i+4]*a[i+4]; r5 += a[i+5]*a[i+5];
        r6 += a[i+6]*a[i+6]; r7 += a[i+7]*a[i+7];
    }
    return ((r0+r1)+(r2+r3))+((r4+r5)+(r6+r7));
}

__device__ __forceinline__ float np_sumsq64_lds(const float* sh) {
#pragma clang fp contract(off)
    float r0=0.f,r1=0.f,r2=0.f,r3=0.f,r4=0.f,r5=0.f,r6=0.f,r7=0.f;
#pragma unroll
    for (int i = 0; i < 64; i += 8) {
        float a0=sh[i+0],a1=sh[i+1],a2=sh[i+2],a3=sh[i+3];
        float a4=sh[i+4],a5=sh[i+5],a6=sh[i+6],a7=sh[i+7];
        r0 += a0*a0; r1 += a1*a1; r2 += a2*a2; r3 += a3*a3;
        r4 += a4*a4; r5 += a5*a5; r6 += a6*a6; r7 += a7*a7;
    }
    return ((r0+r1)+(r2+r3))+((r4+r5)+(r6+r7));
}

__device__ __forceinline__ float np_sumsq64_str(const float* sh, int stride) {
#pragma clang fp contract(off)
    float r0=0.f,r1=0.f,r2=0.f,r3=0.f,r4=0.f,r5=0.f,r6=0.f,r7=0.f;
#pragma unroll
    for (int i = 0; i < 64; i += 8) {
        float a0=sh[(i+0)*stride],a1=sh[(i+1)*stride];
        float a2=sh[(i+2)*stride],a3=sh[(i+3)*stride];
        float a4=sh[(i+4)*stride],a5=sh[(i+5)*stride];
        float a6=sh[(i+6)*stride],a7=sh[(i+7)*stride];
        r0 += a0*a0; r1 += a1*a1; r2 += a2*a2; r3 += a3*a3;
        r4 += a4*a4; r5 += a5*a5; r6 += a6*a6; r7 += a7*a7;
    }
    return ((r0+r1)+(r2+r3))+((r4+r5)+(r6+r7));
}

// ---------------------------------------------------------------------------
// Prep (merged): B-fragments of the hi/lo bf16 split of emb^T + e2 table.
__global__ __launch_bounds__(256) void vq_prep(const float* __restrict__ emb,
                                               short* __restrict__ ebh,
                                               short* __restrict__ ebl,
                                               float* __restrict__ e2) {
    int t    = blockIdx.x * 256 + threadIdx.x;   // 8192 = 128 slots * 64 lanes
    int l    = t & 63;
    int slot = t >> 6;
    int ct = slot >> 1, ks = slot & 1;
    int code  = ct*16 + (l & 15);
    int dbase = ks*32 + (l >> 4)*8;
    const float* ep = emb + (size_t)code*DD + dbase;
    short8v h, lo;
#pragma unroll
    for (int j = 0; j < 8; ++j) {
        float v = ep[j];
        unsigned short hh = bf16_rne(v);
        h[j]  = (short)hh;
        lo[j] = (short)bf16_rne(v - bf16_tof(hh));
    }
    ((short8v*)ebh)[t] = h;
    ((short8v*)ebl)[t] = lo;

    if (blockIdx.x < 4) {                        // e2: 1024 threads total
        int k = blockIdx.x * 256 + threadIdx.x;
        float ek[DD];
        const float4* p = reinterpret_cast<const float4*>(emb + (size_t)k * DD);
#pragma unroll
        for (int q = 0; q < 16; ++q) {
            float4 v = p[q];
            ek[4*q+0]=v.x; ek[4*q+1]=v.y; ek[4*q+2]=v.z; ek[4*q+3]=v.w;
        }
        e2[k] = np_sumsq64(ek);
    }
}

// ---------------------------------------------------------------------------
// Main (fused): 128 px/block x 1024 codes via bf16 MFMA (3-pass hi/lo).
// Round-26: prefetch moved AFTER the barrier. Round-25's order
// [prefetch; publish; barrier] made the compiler's implicit vmcnt(0)
// before s_barrier drain the JUST-issued prefetch -> full L2 latency per
// iteration. Now [publish; barrier; prefetch; scores; MFMA]: the only
// outstanding vmem at any barrier is a load issued a full iteration ago.
// Argmin arithmetic bit-identical to rounds 17-25.
__global__ __launch_bounds__(256, 4) void vq_main(
        const float* __restrict__ z, const float* __restrict__ emb,
        const short* __restrict__ ebh, const short* __restrict__ ebl,
        const float* __restrict__ e2,
        int* __restrict__ idx, int* __restrict__ list, int* __restrict__ cnt,
        float* __restrict__ zrows, int zcap,
        float* __restrict__ out, double* __restrict__ partial) {
    __shared__ float zsh[DD * ZSTR];               // 32768 B
    __shared__ __align__(16) char ovl[8192];       // staging buf / post-loop
    short8v* sbp    = (short8v*)ovl;               // sb[buf][half][slot]
    int*     idx_loc= (int*)ovl;                   // post-loop overlay
    int*     flpx   = (int*)(ovl + 512);
    int*     flslot = (int*)(ovl + 1024);
    int*     q_px   = (int*)(ovl + 1536);
    int*     q_k1   = (int*)(ovl + 2048);
    int*     q_k2   = (int*)(ovl + 2560);
    int*     cnts   = (int*)(ovl + 3072);          // [0]=nfl [1]=n2c
    double*  sred   = (double*)(ovl + 4096);       // 2048 B

    const int tid = threadIdx.x;
    const int w   = tid >> 6;
    const int l   = tid & 63;
    const int lr  = l & 15;
    const int lg  = l >> 4;
    const int b   = blockIdx.x >> 5;          // 32 blocks per image
    const int hw0 = (blockIdx.x & 31) * PXB;
    const float* zb = z + (size_t)b*(DD*HWSZ) + hw0;
    const short8v* EBH = (const short8v*)ebh;
    const short8v* EBL = (const short8v*)ebl;
    const int slot = tid & 127, half = tid >> 7;   // staging role
    const short8v* EBX = half ? EBL : EBH;

    {   // coalesced stage: 2 d-rows per iteration (256 thr = 2 x 128 px)
        const int row = tid >> 7, col = tid & 127;
#pragma unroll 8
        for (int d0 = 0; d0 < DD; d0 += 2)
            zsh[(d0+row)*ZSTR + col] = zb[(size_t)(d0+row)*HWSZ + col];
    }
    // B-frag tile 0 into buf 0
    sbp[half*128 + slot] = EBX[slot];
    __syncthreads();

    // A-frags from LDS. ah/al[rt][ks]; elem j <-> d = ks*32+lg*8+j.
    short8v ah[2][2], al[2][2];
#pragma unroll
    for (int rt = 0; rt < 2; ++rt) {
#pragma unroll
        for (int ks = 0; ks < 2; ++ks) {
            int px = w*32 + rt*16 + lr;
            int dbase = ks*32 + lg*8;
#pragma unroll
            for (int j = 0; j < 8; ++j) {
                float v = zsh[(dbase + j)*ZSTR + px];
                unsigned short hh = bf16_rne(v);
                ah[rt][ks][j] = (short)hh;
                al[rt][ks][j] = (short)bf16_rne(v - bf16_tof(hh));
            }
        }
    }

    // packed top-3 keys only (no index registers)
    float b1a[2][4], b2a[2][4], b3a[2][4];
#pragma unroll
    for (int rt = 0; rt < 2; ++rt)
#pragma unroll
        for (int r = 0; r < 4; ++r) {
            b1a[rt][r] = 3.4e38f; b2a[rt][r] = 3.4e38f; b3a[rt][r] = 3.4e38f;
        }

    float4v  accP[2];
    float    e2P;
    unsigned kfP;
    short8v  stgC;

    // ---- peel ct = 0: prefetch tile 1, MFMA tile 0 from LDS buf 0 ----
    {
        stgC = EBX[128 + slot];                    // tile 1 (covered by peel)
        short8v bh0 = sbp[l],       bh1 = sbp[64+l];
        short8v bl0 = sbp[128+l],   bl1 = sbp[192+l];
        e2P = e2[lr] + SHIFT;
        kfP = (unsigned)lr;
#pragma unroll
        for (int rt = 0; rt < 2; ++rt) {
            float4v acc = {0.f, 0.f, 0.f, 0.f};
            acc = __builtin_amdgcn_mfma_f32_16x16x32_bf16(ah[rt][0], bh0, acc, 0,0,0);
            acc = __builtin_amdgcn_mfma_f32_16x16x32_bf16(ah[rt][1], bh1, acc, 0,0,0);
            acc = __builtin_amdgcn_mfma_f32_16x16x32_bf16(ah[rt][0], bl0, acc, 0,0,0);
            acc = __builtin_amdgcn_mfma_f32_16x16x32_bf16(ah[rt][1], bl1, acc, 0,0,0);
            acc = __builtin_amdgcn_mfma_f32_16x16x32_bf16(al[rt][0], bh0, acc, 0,0,0);
            acc = __builtin_amdgcn_mfma_f32_16x16x32_bf16(al[rt][1], bh1, acc, 0,0,0);
            accP[rt] = acc;
        }
    }

#pragma unroll 1
    for (int ct = 1; ct < 64; ++ct) {
        const int base = (ct & 1) * 256;
        // (1) publish tile ct (loaded a FULL iteration ago -> data arrived;
        //     the implicit vmcnt wait here is on an already-arrived load)
        sbp[base + half*128 + slot] = stgC;
        __syncthreads();
        // (2) prefetch tile ct+1 AFTER the barrier so the barrier's implicit
        //     vmcnt(0) never drains a just-issued load (round-25 flaw)
        stgC = EBX[((ct+1) & 63)*128 + slot];

        // (3) process PREVIOUS iteration's scores (covers prefetch latency)
#pragma unroll
        for (int rt = 0; rt < 2; ++rt)
#pragma unroll
            for (int r = 0; r < 4; ++r) {
                float s = __builtin_fmaf(-2.f, accP[rt][r], e2P);
                float p = __uint_as_float(
                    (__float_as_uint(s) & ~1023u) | kfP);
                float ob1 = b1a[rt][r], ob2 = b2a[rt][r];
                b1a[rt][r] = fminf(ob1, p);
                b2a[rt][r] = __builtin_amdgcn_fmed3f(ob1, ob2, p);
                b3a[rt][r] = __builtin_amdgcn_fmed3f(ob2, b3a[rt][r], p);
            }

        // (4) MFMA chain from LDS (same accumulation order as r17-25)
        {
            short8v bh0 = sbp[base + l],     bh1 = sbp[base + 64+l];
            short8v bl0 = sbp[base + 128+l], bl1 = sbp[base + 192+l];
#pragma unroll
            for (int rt = 0; rt < 2; ++rt) {
                float4v acc = {0.f, 0.f, 0.f, 0.f};
                acc = __builtin_amdgcn_mfma_f32_16x16x32_bf16(ah[rt][0], bh0, acc, 0,0,0);
                acc = __builtin_amdgcn_mfma_f32_16x16x32_bf16(ah[rt][1], bh1, acc, 0,0,0);
                acc = __builtin_amdgcn_mfma_f32_16x16x32_bf16(ah[rt][0], bl0, acc, 0,0,0);
                acc = __builtin_amdgcn_mfma_f32_16x16x32_bf16(ah[rt][1], bl1, acc, 0,0,0);
                acc = __builtin_amdgcn_mfma_f32_16x16x32_bf16(al[rt][0], bh0, acc, 0,0,0);
                acc = __builtin_amdgcn_mfma_f32_16x16x32_bf16(al[rt][1], bh1, acc, 0,0,0);
                accP[rt] = acc;
            }
        }
        e2P = e2[ct*16 + lr] + SHIFT;
        kfP = (unsigned)(ct*16 + lr);
    }

    // ---- drain: scores of ct = 63 (registers only) ----
#pragma unroll
    for (int rt = 0; rt < 2; ++rt)
#pragma unroll
        for (int r = 0; r < 4; ++r) {
            float s = __builtin_fmaf(-2.f, accP[rt][r], e2P);
            float p = __uint_as_float((__float_as_uint(s) & ~1023u) | kfP);
            float ob1 = b1a[rt][r], ob2 = b2a[rt][r];
            b1a[rt][r] = fminf(ob1, p);
            b2a[rt][r] = __builtin_amdgcn_fmed3f(ob1, ob2, p);
            b3a[rt][r] = __builtin_amdgcn_fmed3f(ob2, b3a[rt][r], p);
        }

    // staging buffer now dead; reuse ovl for queues/epilogue
    __syncthreads();
    if (tid < 2) cnts[tid] = 0;
    __syncthreads();
    int& nfl = cnts[0];
    int& n2c = cnts[1];

#pragma unroll
    for (int rt = 0; rt < 2; ++rt) {
#pragma unroll
        for (int r = 0; r < 4; ++r) {
            float b1 = b1a[rt][r], b2 = b2a[rt][r], b3 = b3a[rt][r];
#pragma unroll
            for (int m = 1; m < 16; m <<= 1) {   // sorted-triple min-merge
                float o1 = __shfl_xor(b1, m, 64);
                float o2 = __shfl_xor(b2, m, 64);
                float o3 = __shfl_xor(b3, m, 64);
                float mx  = fmaxf(b1, o1);
                float mn2 = fminf(b2, o2);
                float n1 = fminf(b1, o1);
                float n2 = fminf(mx, mn2);
                float n3 = fminf(fminf(fmaxf(mn2, mx), fmaxf(b2, o2)),
                                 fminf(b3, o3));
                b1 = n1; b2 = n2; b3 = n3;
            }
            if (lr == 0) {
                int i1 = (int)(__float_as_uint(b1) & 1023u);   // all keys > 0
                int pxl = w*32 + rt*16 + lg*4 + r;             // local pixel
                int n   = b*HWSZ + hw0 + pxl;
                idx[n] = i1;
                idx_loc[pxl] = i1;
                if (b2 - b1 <= BAND) {
                    if (b3 - b1 <= BAND) {                 // 3+ in band: full
                        int p = atomicAdd(cnt, 1);
                        list[p] = n;
                        int j = atomicAdd(&nfl, 1);
                        flpx[j] = pxl; flslot[j] = p;
                    } else {                               // exactly {i1,i2}
                        int i2 = (int)(__float_as_uint(b2) & 1023u);
                        int j = atomicAdd(&n2c, 1);
                        q_px[j] = pxl; q_k1[j] = i1; q_k2[j] = i2;
                    }
                }
            }
        }
    }

    __syncthreads();
    // ---- 2-candidate exact resolve (ref fp32 bits), one thread per row ----
    if (tid < n2c) {
        int px = q_px[tid], k1 = q_k1[tid], k2 = q_k2[tid];
        float z2 = np_sumsq64_str(&zsh[px], ZSTR);
        const float* ep1 = emb + (size_t)k1 * DD;
        const float* ep2 = emb + (size_t)k2 * DD;
        float s1 = 0.f, s2 = 0.f;
#pragma unroll
        for (int d = 0; d < DD; ++d) {                 // d-ascending chains
            float zd = zsh[d*ZSTR + px];
            s1 = __builtin_fmaf(zd, ep1[d], s1);
            s2 = __builtin_fmaf(zd, ep2[d], s2);
        }
        float B1v, B2v;
        {
#pragma clang fp contract(off)
            float A1 = z2 + e2[k1]; B1v = __builtin_fmaf(-2.f, s1, A1);
            float A2 = z2 + e2[k2]; B2v = __builtin_fmaf(-2.f, s2, A2);
        }
        int win;
        if (k1 < k2) win = (B2v < B1v) ? k2 : k1;      // first-min tie-break
        else         win = (B1v < B2v) ? k1 : k2;
        idx[b*HWSZ + hw0 + px] = win;
        idx_loc[px] = win;
    }

    // ---- packed z copy for full-exact rows (coalesced) ----
    __syncthreads();
    int nf = nfl;
    for (int j0 = 0; j0 < nf; j0 += 4) {
        int jj = j0 + (tid >> 6);
        if (jj < nf) {
            int sl = flslot[jj];
            if (sl < zcap) {
                int d = tid & 63;
                zrows[(size_t)sl*64 + d] = zsh[d*ZSTR + flpx[jj]];
            }
        }
    }
    __syncthreads();

    // ---- fused epilogue: 2 threads per px (d-halves); z from LDS ----
    {
        const int px = tid & 127;
        const int dh = tid >> 7;              // 0 or 1: d in [dh*32, dh*32+32)
        const int ki = idx_loc[px];
        const float4* ep = reinterpret_cast<const float4*>(
                               emb + (size_t)ki*DD + dh*32);
        float* op = out + (size_t)b*(DD*HWSZ) + (size_t)(dh*32)*HWSZ + hw0 + px;
        float lsum = 0.f;
#pragma unroll
        for (int q = 0; q < 8; ++q) {
            float4 v = ep[q];
            int d = dh*32 + 4*q;
            float z0 = zsh[(d+0)*ZSTR + px];
            float z1 = zsh[(d+1)*ZSTR + px];
            float z2v = zsh[(d+2)*ZSTR + px];
            float z3 = zsh[(d+3)*ZSTR + px];
            op[(size_t)(4*q+0)*HWSZ] = v.x;
            op[(size_t)(4*q+1)*HWSZ] = v.y;
            op[(size_t)(4*q+2)*HWSZ] = v.z;
            op[(size_t)(4*q+3)*HWSZ] = v.w;
            float f0 = v.x - z0, f1 = v.y - z1, f2 = v.z - z2v, f3 = v.w - z3;
            lsum = __builtin_fmaf(f0, f0, lsum);
            lsum = __builtin_fmaf(f1, f1, lsum);
            lsum = __builtin_fmaf(f2, f2, lsum);
            lsum = __builtin_fmaf(f3, f3, lsum);
        }
        if (dh == 0) out[IDX_OUT_OFF + b*HWSZ + hw0 + px] = (float)ki;
        sred[tid] = (double)lsum;
    }
    __syncthreads();
#pragma unroll
    for (int sdown = 128; sdown > 0; sdown >>= 1) {
        if (tid < sdown) sred[tid] += sred[tid + sdown];
        __syncthreads();
    }
    if (tid == 0) partial[blockIdx.x] = sred[0];
}

// ---------------------------------------------------------------------------
// Full exact pass v8: ONE BLOCK per rare flagged row (3+ in band). Computes
// the true ref-fp32 argmin AND patches the fused outputs.
__global__ __launch_bounds__(256) void vq_exact8(
        const float* __restrict__ z, const float* __restrict__ emb,
        const float* __restrict__ e2, const float* __restrict__ zrows,
        const int* __restrict__ list, const int* __restrict__ cnt,
        int zcap, int* __restrict__ idx, float* __restrict__ out,
        double* __restrict__ delta) {
    __shared__ float zsh[DD];
    __shared__ float rbv[256];
    __shared__ int   rbi[256];
    __shared__ double dred[64];
    const int tid = threadIdx.x;
    const int C   = *cnt;

    for (int i = blockIdx.x; i < C; i += gridDim.x) {
        const int n = list[i];
        if (tid < 64) {
            if (i < zcap) {
                zsh[tid] = zrows[(size_t)i*64 + tid];      // coalesced line
            } else {
                zsh[tid] = z[(size_t)(n>>12)*(DD*HWSZ) + (n&4095)
                             + (size_t)tid*HWSZ];
            }
        }
        __syncthreads();

        const float z2 = np_sumsq64_lds(zsh);

        float bestv = 3.4e38f; int bi = 0x7fffffff;
#pragma unroll
        for (int c = 0; c < 4; ++c) {                  // k = tid + c*256, asc
            int k = c*256 + tid;
            const float4* ep = reinterpret_cast<const float4*>(emb + (size_t)k*DD);
            float s = 0.f;
#pragma unroll
            for (int q = 0; q < 16; ++q) {             // d-ascending chain
                float4 v = ep[q];
                s = __builtin_fmaf(zsh[4*q+0], v.x, s);
                s = __builtin_fmaf(zsh[4*q+1], v.y, s);
                s = __builtin_fmaf(zsh[4*q+2], v.z, s);
                s = __builtin_fmaf(zsh[4*q+3], v.w, s);
            }
            float Bv;
            {
#pragma clang fp contract(off)
                float A = z2 + e2[k];
                Bv = __builtin_fmaf(-2.f, s, A);
            }
            if (Bv < bestv) { bestv = Bv; bi = k; }    // first-min (k asc)
        }

        rbv[tid] = bestv; rbi[tid] = bi;
        __syncthreads();
#pragma unroll
        for (int sdown = 128; sdown > 0; sdown >>= 1) {
            if (tid < sdown) {
                float ov = rbv[tid + sdown]; int oi = rbi[tid + sdown];
                if (ov < rbv[tid] || (ov == rbv[tid] && oi < rbi[tid])) {
                    rbv[tid] = ov; rbi[tid] = oi;
                }
            }
            __syncthreads();
        }
        const int win = rbi[0];
        const int old = idx[n];
        if (win != old) {                               // block-uniform branch
            const int bq = n >> 12, hw = n & 4095;
            if (tid < 64) {
                float zd = zsh[tid];
                float en = emb[(size_t)win*DD + tid];
                float eo = emb[(size_t)old*DD + tid];
                out[(size_t)bq*(DD*HWSZ) + (size_t)tid*HWSZ + hw] = en;
                float dn = en - zd, dl = eo - zd;
                dred[tid] = (double)(dn*dn) - (double)(dl*dl);
            }
            __syncthreads();
            if (tid == 0) {
                double s = 0.0;
                for (int j = 0; j < 64; ++j) s += dred[j];
                atomicAdd(delta, s);
                idx[n] = win;
                out[IDX_OUT_OFF + n] = (float)win;
            }
        }
        __syncthreads();
    }
}

// ---------------------------------------------------------------------------
__global__ __launch_bounds__(256) void vq_finalize(
        const double* __restrict__ part, const double* __restrict__ delta,
        float* __restrict__ out) {
    __shared__ double sred[256];
    int t = threadIdx.x;
    sred[t] = part[t] + part[t + 256] + part[t + 512] + part[t + 768];
    __syncthreads();
#pragma unroll
    for (int sdown = 128; sdown > 0; sdown >>= 1) {
        if (t < sdown) sred[t] += sred[t + sdown];
        __syncthreads();
    }
    if (t == 0) {
        double m = (sred[0] + *delta) / (double)NELEM;
        out[LOSS_OFF]     = (float)m;
        out[LOSS_OFF + 1] = (float)(0.25 * m);
    }
}

// ---------------------------------------------------------------------------
extern "C" void kernel_launch(void* const* d_in, const int* in_sizes, int n_in,
                              void* d_out, int out_size, void* d_ws, size_t ws_size,
                              hipStream_t stream) {
    const float* z   = (const float*)d_in[0];
    const float* emb = (const float*)d_in[1];
    float* out = (float*)d_out;
    char*  ws  = (char*)d_ws;

    float*  e2p   = (float*)(ws + WS_E2);
    short*  ebh   = (short*)(ws + WS_EBH);
    short*  ebl   = (short*)(ws + WS_EBL);
    int*    idxp  = (int*)(ws + WS_IDX);
    int*    lst   = (int*)(ws + WS_LIST);
    int*    cntp  = (int*)(ws + WS_CNT);
    double* delta = (double*)(ws + WS_CNT + 8);
    double* part  = (double*)(ws + WS_PART);
    float*  zrows = (float*)(ws + WS_ZROWS);

    long long zrem = (long long)ws_size - (long long)WS_ZROWS;
    int zcap = zrem > 0 ? (int)(zrem / 256) : 0;
    if (zcap > NPIX) zcap = NPIX;

    hipMemsetAsync(cntp, 0, 16, stream);     // cnt + loss delta
    vq_prep     <<<32,       256, 0, stream>>>(emb, ebh, ebl, e2p);
    vq_main     <<<NPIX/PXB, 256, 0, stream>>>(z, emb, ebh, ebl, e2p, idxp,
                                               lst, cntp, zrows, zcap,
                                               out, part);
    vq_exact8   <<<512,      256, 0, stream>>>(z, emb, e2p, zrows, lst, cntp,
                                               zcap, idxp, out, delta);
    vq_finalize <<<1,        256, 0, stream>>>(part, delta, out);
}

// Round 27
// 116.276 us; speedup vs baseline: 1.0746x; 1.0312x over previous
//
#include <hip/hip_runtime.h>

// Problem geometry (fixed by setup_inputs)
#define BB 32
#define DD 64
#define HWSZ 4096                  // H*W
#define KK 1024
#define NPIX (BB*HWSZ)             // 131072
#define NELEM (NPIX*DD)            // 8388608

// Output layout (concatenated float32)
#define IDX_OUT_OFF NELEM
#define LOSS_OFF (IDX_OUT_OFF + NPIX)

// Workspace layout (bytes)
#define WS_E2    0                        // 4 KB
#define WS_EBH   4096                     // 128 KB  B-frags hi
#define WS_EBL   (WS_EBH + KK*DD*2)       // 128 KB  B-frags lo
#define WS_IDX   (WS_EBL + KK*DD*2)       // 512 KB
#define WS_LIST  (WS_IDX + NPIX*4)        // 512 KB
#define WS_CNT   (WS_LIST + NPIX*4)       // 64 B: cnt@+0, loss-delta double@+8
#define WS_PART  (WS_CNT + 64)            // 16 KB
#define WS_ZROWS (WS_PART + 16384)        // packed z rows (full-exact rows)

#define PXB 128
#define ZSTR 129                   // zsh row stride

// Positive shift keeps all scores > 0 (sign-free key packing); BAND budget
// as rounds 17-26 (fast-vs-ref ~2e-5 + 10-bit clearing <= 6e-5 pairwise).
#define SHIFT 0.25f
#define BAND 2.5e-4f

typedef __attribute__((ext_vector_type(8))) short short8v;
typedef __attribute__((ext_vector_type(4))) float float4v;

__device__ __forceinline__ unsigned short bf16_rne(float f) {
    unsigned u = __float_as_uint(f);
    u += 0x7fffu + ((u >> 16) & 1u);
    return (unsigned short)(u >> 16);
}
__device__ __forceinline__ float bf16_tof(unsigned short h) {
    return __uint_as_float(((unsigned)h) << 16);
}

// numpy-style fp32 sum of 64 squares (squares rounded separately; no FMA).
__device__ __forceinline__ float np_sumsq64(const float* a) {
#pragma clang fp contract(off)
    float r0=0.f,r1=0.f,r2=0.f,r3=0.f,r4=0.f,r5=0.f,r6=0.f,r7=0.f;
#pragma unroll
    for (int i = 0; i < 64; i += 8) {
        r0 += a[i+0]*a[i+0]; r1 += a[i+1]*a[i+1];
        r2 += a[i+2]*a[i+2]; r3 += a[i+3]*a[i+3];
        r4 += a[i+4]*a[i+4]; r5 += a[i+5]*a[i+5];
        r6 += a[i+6]*a[i+6]; r7 += a[i+7]*a[i+7];
    }
    return ((r0+r1)+(r2+r3))+((r4+r5)+(r6+r7));
}

__device__ __forceinline__ float np_sumsq64_lds(const float* sh) {
#pragma clang fp contract(off)
    float r0=0.f,r1=0.f,r2=0.f,r3=0.f,r4=0.f,r5=0.f,r6=0.f,r7=0.f;
#pragma unroll
    for (int i = 0; i < 64; i += 8) {
        float a0=sh[i+0],a1=sh[i+1],a2=sh[i+2],a3=sh[i+3];
        float a4=sh[i+4],a5=sh[i+5],a6=sh[i+6],a7=sh[i+7];
        r0 += a0*a0; r1 += a1*a1; r2 += a2*a2; r3 += a3*a3;
        r4 += a4*a4; r5 += a5*a5; r6 += a6*a6; r7 += a7*a7;
    }
    return ((r0+r1)+(r2+r3))+((r4+r5)+(r6+r7));
}

__device__ __forceinline__ float np_sumsq64_str(const float* sh, int stride) {
#pragma clang fp contract(off)
    float r0=0.f,r1=0.f,r2=0.f,r3=0.f,r4=0.f,r5=0.f,r6=0.f,r7=0.f;
#pragma unroll
    for (int i = 0; i < 64; i += 8) {
        float a0=sh[(i+0)*stride],a1=sh[(i+1)*stride];
        float a2=sh[(i+2)*stride],a3=sh[(i+3)*stride];
        float a4=sh[(i+4)*stride],a5=sh[(i+5)*stride];
        float a6=sh[(i+6)*stride],a7=sh[(i+7)*stride];
        r0 += a0*a0; r1 += a1*a1; r2 += a2*a2; r3 += a3*a3;
        r4 += a4*a4; r5 += a5*a5; r6 += a6*a6; r7 += a7*a7;
    }
    return ((r0+r1)+(r2+r3))+((r4+r5)+(r6+r7));
}

// ---------------------------------------------------------------------------
// Prep (merged): B-fragments of the hi/lo bf16 split of emb^T + e2 table.
__global__ __launch_bounds__(256) void vq_prep(const float* __restrict__ emb,
                                               short* __restrict__ ebh,
                                               short* __restrict__ ebl,
                                               float* __restrict__ e2) {
    int t    = blockIdx.x * 256 + threadIdx.x;   // 8192 = 128 slots * 64 lanes
    int l    = t & 63;
    int slot = t >> 6;
    int ct = slot >> 1, ks = slot & 1;
    int code  = ct*16 + (l & 15);
    int dbase = ks*32 + (l >> 4)*8;
    const float* ep = emb + (size_t)code*DD + dbase;
    short8v h, lo;
#pragma unroll
    for (int j = 0; j < 8; ++j) {
        float v = ep[j];
        unsigned short hh = bf16_rne(v);
        h[j]  = (short)hh;
        lo[j] = (short)bf16_rne(v - bf16_tof(hh));
    }
    ((short8v*)ebh)[t] = h;
    ((short8v*)ebl)[t] = lo;

    if (blockIdx.x < 4) {                        // e2: 1024 threads total
        int k = blockIdx.x * 256 + threadIdx.x;
        float ek[DD];
        const float4* p = reinterpret_cast<const float4*>(emb + (size_t)k * DD);
#pragma unroll
        for (int q = 0; q < 16; ++q) {
            float4 v = p[q];
            ek[4*q+0]=v.x; ek[4*q+1]=v.y; ek[4*q+2]=v.z; ek[4*q+3]=v.w;
        }
        e2[k] = np_sumsq64(ek);
    }
}

// ---------------------------------------------------------------------------
// Main (fused): 128 px/block x 1024 codes via bf16 MFMA (3-pass hi/lo).
// Software-pipelined: scores one iter behind MFMAs; register B-frag reads
// (round-20 configuration -- empirically the best of 7 schedule variants).
__global__ __launch_bounds__(256, 4) void vq_main(
        const float* __restrict__ z, const float* __restrict__ emb,
        const short* __restrict__ ebh, const short* __restrict__ ebl,
        const float* __restrict__ e2,
        int* __restrict__ idx, int* __restrict__ list, int* __restrict__ cnt,
        float* __restrict__ zrows, int zcap,
        float* __restrict__ out, double* __restrict__ partial) {
    __shared__ float zsh[DD * ZSTR];     // ~32.25 KB, [d][px] stride 129
    __shared__ int   idx_loc[PXB];
    __shared__ int   flpx[128], flslot[128];
    __shared__ int   q_px[128], q_k1[128], q_k2[128];
    __shared__ int   nfl, n2c;
    __shared__ double sred[256];
    const int tid = threadIdx.x;
    const int w   = tid >> 6;
    const int l   = tid & 63;
    const int lr  = l & 15;
    const int lg  = l >> 4;
    const int b   = blockIdx.x >> 5;          // 32 blocks per image
    const int hw0 = (blockIdx.x & 31) * PXB;
    const float* zb = z + (size_t)b*(DD*HWSZ) + hw0;

    if (tid == 0) { nfl = 0; n2c = 0; }
    {   // coalesced stage: 2 d-rows per iteration (256 thr = 2 x 128 px)
        const int row = tid >> 7, col = tid & 127;
#pragma unroll 8
        for (int d0 = 0; d0 < DD; d0 += 2)
            zsh[(d0+row)*ZSTR + col] = zb[(size_t)(d0+row)*HWSZ + col];
    }
    __syncthreads();

    // A-frags from LDS. ah/al[rt][ks]; elem j <-> d = ks*32+lg*8+j.
    short8v ah[2][2], al[2][2];
#pragma unroll
    for (int rt = 0; rt < 2; ++rt) {
#pragma unroll
        for (int ks = 0; ks < 2; ++ks) {
            int px = w*32 + rt*16 + lr;
            int dbase = ks*32 + lg*8;
#pragma unroll
            for (int j = 0; j < 8; ++j) {
                float v = zsh[(dbase + j)*ZSTR + px];
                unsigned short hh = bf16_rne(v);
                ah[rt][ks][j] = (short)hh;
                al[rt][ks][j] = (short)bf16_rne(v - bf16_tof(hh));
            }
        }
    }

    // packed top-3 keys only (no index registers)
    float b1a[2][4], b2a[2][4], b3a[2][4];
#pragma unroll
    for (int rt = 0; rt < 2; ++rt)
#pragma unroll
        for (int r = 0; r < 4; ++r) {
            b1a[rt][r] = 3.4e38f; b2a[rt][r] = 3.4e38f; b3a[rt][r] = 3.4e38f;
        }

    const short8v* EBH = (const short8v*)ebh;
    const short8v* EBL = (const short8v*)ebl;

    float4v  accP[2];
    float    e2P;
    unsigned kfP;

    // ---- peeled ct = 0: MFMA only, fills the pipeline ----
    {
        short8v bh0 = EBH[l],  bh1 = EBH[64 + l];
        short8v bl0 = EBL[l],  bl1 = EBL[64 + l];
        e2P = e2[lr] + SHIFT;
        kfP = (unsigned)lr;
#pragma unroll
        for (int rt = 0; rt < 2; ++rt) {
            float4v acc = {0.f, 0.f, 0.f, 0.f};
            acc = __builtin_amdgcn_mfma_f32_16x16x32_bf16(ah[rt][0], bh0, acc, 0,0,0);
            acc = __builtin_amdgcn_mfma_f32_16x16x32_bf16(ah[rt][1], bh1, acc, 0,0,0);
            acc = __builtin_amdgcn_mfma_f32_16x16x32_bf16(ah[rt][0], bl0, acc, 0,0,0);
            acc = __builtin_amdgcn_mfma_f32_16x16x32_bf16(ah[rt][1], bl1, acc, 0,0,0);
            acc = __builtin_amdgcn_mfma_f32_16x16x32_bf16(al[rt][0], bh0, acc, 0,0,0);
            acc = __builtin_amdgcn_mfma_f32_16x16x32_bf16(al[rt][1], bh1, acc, 0,0,0);
            accP[rt] = acc;
        }
    }

#pragma unroll 1
    for (int ct = 1; ct < 64; ++ct) {
        // (1) issue this iteration's B-frag loads
        int s0 = ct*128 + l;
        short8v bh0 = EBH[s0], bh1 = EBH[s0+64];
        short8v bl0 = EBL[s0], bl1 = EBL[s0+64];
        float   e2c = e2[ct*16 + lr] + SHIFT;

        // (2) process PREVIOUS iteration's scores (covers load latency)
#pragma unroll
        for (int rt = 0; rt < 2; ++rt)
#pragma unroll
            for (int r = 0; r < 4; ++r) {
                float s = __builtin_fmaf(-2.f, accP[rt][r], e2P);
                float p = __uint_as_float(
                    (__float_as_uint(s) & ~1023u) | kfP);
                float ob1 = b1a[rt][r], ob2 = b2a[rt][r];
                b1a[rt][r] = fminf(ob1, p);
                b2a[rt][r] = __builtin_amdgcn_fmed3f(ob1, ob2, p);
                b3a[rt][r] = __builtin_amdgcn_fmed3f(ob2, b3a[rt][r], p);
            }

        // (3) MFMA chain for this iteration (same order as rounds 17-26)
#pragma unroll
        for (int rt = 0; rt < 2; ++rt) {
            float4v acc = {0.f, 0.f, 0.f, 0.f};
            acc = __builtin_amdgcn_mfma_f32_16x16x32_bf16(ah[rt][0], bh0, acc, 0,0,0);
            acc = __builtin_amdgcn_mfma_f32_16x16x32_bf16(ah[rt][1], bh1, acc, 0,0,0);
            acc = __builtin_amdgcn_mfma_f32_16x16x32_bf16(ah[rt][0], bl0, acc, 0,0,0);
            acc = __builtin_amdgcn_mfma_f32_16x16x32_bf16(ah[rt][1], bl1, acc, 0,0,0);
            acc = __builtin_amdgcn_mfma_f32_16x16x32_bf16(al[rt][0], bh0, acc, 0,0,0);
            acc = __builtin_amdgcn_mfma_f32_16x16x32_bf16(al[rt][1], bh1, acc, 0,0,0);
            accP[rt] = acc;
        }
        e2P = e2c;
        kfP = (unsigned)(ct*16 + lr);
    }

    // ---- drain: scores of ct = 63 ----
#pragma unroll
    for (int rt = 0; rt < 2; ++rt)
#pragma unroll
        for (int r = 0; r < 4; ++r) {
            float s = __builtin_fmaf(-2.f, accP[rt][r], e2P);
            float p = __uint_as_float((__float_as_uint(s) & ~1023u) | kfP);
            float ob1 = b1a[rt][r], ob2 = b2a[rt][r];
            b1a[rt][r] = fminf(ob1, p);
            b2a[rt][r] = __builtin_amdgcn_fmed3f(ob1, ob2, p);
            b3a[rt][r] = __builtin_amdgcn_fmed3f(ob2, b3a[rt][r], p);
        }

#pragma unroll
    for (int rt = 0; rt < 2; ++rt) {
#pragma unroll
        for (int r = 0; r < 4; ++r) {
            float b1 = b1a[rt][r], b2 = b2a[rt][r], b3 = b3a[rt][r];
#pragma unroll
            for (int m = 1; m < 16; m <<= 1) {   // sorted-triple min-merge
                float o1 = __shfl_xor(b1, m, 64);
                float o2 = __shfl_xor(b2, m, 64);
                float o3 = __shfl_xor(b3, m, 64);
                float mx  = fmaxf(b1, o1);
                float mn2 = fminf(b2, o2);
                float n1 = fminf(b1, o1);
                float n2 = fminf(mx, mn2);
                float n3 = fminf(fminf(fmaxf(mn2, mx), fmaxf(b2, o2)),
                                 fminf(b3, o3));
                b1 = n1; b2 = n2; b3 = n3;
            }
            if (lr == 0) {
                int i1 = (int)(__float_as_uint(b1) & 1023u);   // all keys > 0
                int pxl = w*32 + rt*16 + lg*4 + r;             // local pixel
                int n   = b*HWSZ + hw0 + pxl;
                idx[n] = i1;
                idx_loc[pxl] = i1;
                if (b2 - b1 <= BAND) {
                    if (b3 - b1 <= BAND) {                 // 3+ in band: full
                        int p = atomicAdd(cnt, 1);
                        list[p] = n;
                        int j = atomicAdd(&nfl, 1);
                        flpx[j] = pxl; flslot[j] = p;
                    } else {                               // exactly {i1,i2}
                        int i2 = (int)(__float_as_uint(b2) & 1023u);
                        int j = atomicAdd(&n2c, 1);
                        q_px[j] = pxl; q_k1[j] = i1; q_k2[j] = i2;
                    }
                }
            }
        }
    }

    __syncthreads();
    // ---- 2-candidate exact resolve (ref fp32 bits), one thread per row ----
    if (tid < n2c) {
        int px = q_px[tid], k1 = q_k1[tid], k2 = q_k2[tid];
        float z2 = np_sumsq64_str(&zsh[px], ZSTR);
        const float* ep1 = emb + (size_t)k1 * DD;
        const float* ep2 = emb + (size_t)k2 * DD;
        float s1 = 0.f, s2 = 0.f;
#pragma unroll
        for (int d = 0; d < DD; ++d) {                 // d-ascending chains
            float zd = zsh[d*ZSTR + px];
            s1 = __builtin_fmaf(zd, ep1[d], s1);
            s2 = __builtin_fmaf(zd, ep2[d], s2);
        }
        float B1v, B2v;
        {
#pragma clang fp contract(off)
            float A1 = z2 + e2[k1]; B1v = __builtin_fmaf(-2.f, s1, A1);
            float A2 = z2 + e2[k2]; B2v = __builtin_fmaf(-2.f, s2, A2);
        }
        int win;
        if (k1 < k2) win = (B2v < B1v) ? k2 : k1;      // first-min tie-break
        else         win = (B1v < B2v) ? k1 : k2;
        idx[b*HWSZ + hw0 + px] = win;
        idx_loc[px] = win;
    }

    // ---- packed z copy for full-exact rows (coalesced) ----
    __syncthreads();
    int nf = nfl;
    for (int j0 = 0; j0 < nf; j0 += 4) {
        int jj = j0 + (tid >> 6);
        if (jj < nf) {
            int slot = flslot[jj];
            if (slot < zcap) {
                int d = tid & 63;
                zrows[(size_t)slot*64 + d] = zsh[d*ZSTR + flpx[jj]];
            }
        }
    }
    __syncthreads();

    // ---- fused epilogue: 2 threads per px (d-halves); z from LDS ----
    {
        const int px = tid & 127;
        const int dh = tid >> 7;              // 0 or 1: d in [dh*32, dh*32+32)
        const int ki = idx_loc[px];
        const float4* ep = reinterpret_cast<const float4*>(
                               emb + (size_t)ki*DD + dh*32);
        float* op = out + (size_t)b*(DD*HWSZ) + (size_t)(dh*32)*HWSZ + hw0 + px;
        float lsum = 0.f;
#pragma unroll
        for (int q = 0; q < 8; ++q) {
            float4 v = ep[q];
            int d = dh*32 + 4*q;
            float z0 = zsh[(d+0)*ZSTR + px];
            float z1 = zsh[(d+1)*ZSTR + px];
            float z2v = zsh[(d+2)*ZSTR + px];
            float z3 = zsh[(d+3)*ZSTR + px];
            op[(size_t)(4*q+0)*HWSZ] = v.x;
            op[(size_t)(4*q+1)*HWSZ] = v.y;
            op[(size_t)(4*q+2)*HWSZ] = v.z;
            op[(size_t)(4*q+3)*HWSZ] = v.w;
            float f0 = v.x - z0, f1 = v.y - z1, f2 = v.z - z2v, f3 = v.w - z3;
            lsum = __builtin_fmaf(f0, f0, lsum);
            lsum = __builtin_fmaf(f1, f1, lsum);
            lsum = __builtin_fmaf(f2, f2, lsum);
            lsum = __builtin_fmaf(f3, f3, lsum);
        }
        if (dh == 0) out[IDX_OUT_OFF + b*HWSZ + hw0 + px] = (float)ki;
        sred[tid] = (double)lsum;
    }
    __syncthreads();
#pragma unroll
    for (int sdown = 128; sdown > 0; sdown >>= 1) {
        if (tid < sdown) sred[tid] += sred[tid + sdown];
        __syncthreads();
    }
    if (tid == 0) partial[blockIdx.x] = sred[0];
}

// ---------------------------------------------------------------------------
// Full exact pass v8: ONE BLOCK per rare flagged row (3+ in band). Computes
// the true ref-fp32 argmin AND patches the fused outputs.
__global__ __launch_bounds__(256) void vq_exact8(
        const float* __restrict__ z, const float* __restrict__ emb,
        const float* __restrict__ e2, const float* __restrict__ zrows,
        const int* __restrict__ list, const int* __restrict__ cnt,
        int zcap, int* __restrict__ idx, float* __restrict__ out,
        double* __restrict__ delta) {
    __shared__ float zsh[DD];
    __shared__ float rbv[256];
    __shared__ int   rbi[256];
    __shared__ double dred[64];
    const int tid = threadIdx.x;
    const int C   = *cnt;

    for (int i = blockIdx.x; i < C; i += gridDim.x) {
        const int n = list[i];
        if (tid < 64) {
            if (i < zcap) {
                zsh[tid] = zrows[(size_t)i*64 + tid];      // coalesced line
            } else {
                zsh[tid] = z[(size_t)(n>>12)*(DD*HWSZ) + (n&4095)
                             + (size_t)tid*HWSZ];
            }
        }
        __syncthreads();

        const float z2 = np_sumsq64_lds(zsh);

        float bestv = 3.4e38f; int bi = 0x7fffffff;
#pragma unroll
        for (int c = 0; c < 4; ++c) {                  // k = tid + c*256, asc
            int k = c*256 + tid;
            const float4* ep = reinterpret_cast<const float4*>(emb + (size_t)k*DD);
            float s = 0.f;
#pragma unroll
            for (int q = 0; q < 16; ++q) {             // d-ascending chain
                float4 v = ep[q];
                s = __builtin_fmaf(zsh[4*q+0], v.x, s);
                s = __builtin_fmaf(zsh[4*q+1], v.y, s);
                s = __builtin_fmaf(zsh[4*q+2], v.z, s);
                s = __builtin_fmaf(zsh[4*q+3], v.w, s);
            }
            float Bv;
            {
#pragma clang fp contract(off)
                float A = z2 + e2[k];
                Bv = __builtin_fmaf(-2.f, s, A);
            }
            if (Bv < bestv) { bestv = Bv; bi = k; }    // first-min (k asc)
        }

        rbv[tid] = bestv; rbi[tid] = bi;
        __syncthreads();
#pragma unroll
        for (int sdown = 128; sdown > 0; sdown >>= 1) {
            if (tid < sdown) {
                float ov = rbv[tid + sdown]; int oi = rbi[tid + sdown];
                if (ov < rbv[tid] || (ov == rbv[tid] && oi < rbi[tid])) {
                    rbv[tid] = ov; rbi[tid] = oi;
                }
            }
            __syncthreads();
        }
        const int win = rbi[0];
        const int old = idx[n];
        if (win != old) {                               // block-uniform branch
            const int bq = n >> 12, hw = n & 4095;
            if (tid < 64) {
                float zd = zsh[tid];
                float en = emb[(size_t)win*DD + tid];
                float eo = emb[(size_t)old*DD + tid];
                out[(size_t)bq*(DD*HWSZ) + (size_t)tid*HWSZ + hw] = en;
                float dn = en - zd, dl = eo - zd;
                dred[tid] = (double)(dn*dn) - (double)(dl*dl);
            }
            __syncthreads();
            if (tid == 0) {
                double s = 0.0;
                for (int j = 0; j < 64; ++j) s += dred[j];
                atomicAdd(delta, s);
                idx[n] = win;
                out[IDX_OUT_OFF + n] = (float)win;
            }
        }
        __syncthreads();
    }
}

// ---------------------------------------------------------------------------
__global__ __launch_bounds__(256) void vq_finalize(
        const double* __restrict__ part, const double* __restrict__ delta,
        float* __restrict__ out) {
    __shared__ double sred[256];
    int t = threadIdx.x;
    sred[t] = part[t] + part[t + 256] + part[t + 512] + part[t + 768];
    __syncthreads();
#pragma unroll
    for (int sdown = 128; sdown > 0; sdown >>= 1) {
        if (t < sdown) sred[t] += sred[t + sdown];
        __syncthreads();
    }
    if (t == 0) {
        double m = (sred[0] + *delta) / (double)NELEM;
        out[LOSS_OFF]     = (float)m;
        out[LOSS_OFF + 1] = (float)(0.25 * m);
    }
}

// ---------------------------------------------------------------------------
extern "C" void kernel_launch(void* const* d_in, const int* in_sizes, int n_in,
                              void* d_out, int out_size, void* d_ws, size_t ws_size,
                              hipStream_t stream) {
    const float* z   = (const float*)d_in[0];
    const float* emb = (const float*)d_in[1];
    float* out = (float*)d_out;
    char*  ws  = (char*)d_ws;

    float*  e2p   = (float*)(ws + WS_E2);
    short*  ebh   = (short*)(ws + WS_EBH);
    short*  ebl   = (short*)(ws + WS_EBL);
    int*    idxp  = (int*)(ws + WS_IDX);
    int*    lst   = (int*)(ws + WS_LIST);
    int*    cntp  = (int*)(ws + WS_CNT);
    double* delta = (double*)(ws + WS_CNT + 8);
    double* part  = (double*)(ws + WS_PART);
    float*  zrows = (float*)(ws + WS_ZROWS);

    long long zrem = (long long)ws_size - (long long)WS_ZROWS;
    int zcap = zrem > 0 ? (int)(zrem / 256) : 0;
    if (zcap > NPIX) zcap = NPIX;

    hipMemsetAsync(cntp, 0, 16, stream);     // cnt + loss delta
    vq_prep     <<<32,       256, 0, stream>>>(emb, ebh, ebl, e2p);
    vq_main     <<<NPIX/PXB, 256, 0, stream>>>(z, emb, ebh, ebl, e2p, idxp,
                                               lst, cntp, zrows, zcap,
                                               out, part);
    vq_exact8   <<<512,      256, 0, stream>>>(z, emb, e2p, zrows, lst, cntp,
                                               zcap, idxp, out, delta);
    vq_finalize <<<1,        256, 0, stream>>>(part, delta, out);
}